// Round 3
// baseline (184.350 us; speedup 1.0000x reference)
//
#include <hip/hip_runtime.h>
#include <math.h>

#define BATCH 2048
#define PDIM  4096
#define PAR   4086
#define CONS  10
#define NW    192     // 64 (cw1 cols) + 128 (ow1 cols)

typedef __attribute__((ext_vector_type(8))) short bf16x8;
typedef __attribute__((ext_vector_type(8))) unsigned short ushort8;
typedef __attribute__((ext_vector_type(4))) float f32x4;

__device__ __forceinline__ unsigned short f2bf(float f) {
    unsigned int u = __float_as_uint(f);
    u += 0x7FFFu + ((u >> 16) & 1u);      // RTNE
    return (unsigned short)(u >> 16);
}
__device__ __forceinline__ float bf2f(unsigned short u) {
    return __uint_as_float(((unsigned int)u) << 16);
}
__device__ __forceinline__ float fast_tanh(float z) {
    float a = fabsf(z);
    float ex = __expf(-2.f * a);                       // e^-2a
    float th = (1.f - ex) * __builtin_amdgcn_rcpf(1.f + ex);
    return copysignf(th, z);
}

// ============ L1: colmean_part + prep_WT + prep_Wcat (merged) ============
__global__ __launch_bounds__(256) void prep_all_k(const float* __restrict__ mp,
        const float* __restrict__ cw1, const float* __restrict__ ow1,
        float* __restrict__ epart, unsigned short* __restrict__ WT,
        unsigned short* __restrict__ Wcat) {
    __shared__ float tile[64][33];
    const int bid = blockIdx.x, t = threadIdx.x;
    if (bid < 512) {                       // colmean partial: 16 x 32
        int col = (bid & 15) * 256 + t;
        int z = bid >> 4;
        float s = 0.f;
        int r0 = z * 32;
        for (int r = 0; r < 32; ++r) s += mp[(size_t)(r0 + r) * PDIM + col];
        epart[(size_t)z * PDIM + col] = s;
    } else if (bid < 896) {                // prep_WT: 64 k-chunks x 6 j-chunks
        int g = bid - 512;
        int k0 = (g & 63) * 64, j0 = (g >> 6) * 32;
        const float* src; int lds_, jb;
        if (j0 < 64) { src = cw1; lds_ = 64;  jb = j0; }
        else         { src = ow1; lds_ = 128; jb = j0 - 64; }
        int jl = t & 31, kl0 = t >> 5;
        for (int kk = 0; kk < 64; kk += 8)
            tile[kk + kl0][jl] = src[(size_t)(k0 + kk + kl0) * lds_ + jb + jl];
        __syncthreads();
        int kl = t & 63, jl0 = t >> 6;
        for (int jj = 0; jj < 32; jj += 4)
            WT[(size_t)(j0 + jj + jl0) * PDIM + k0 + kl] = f2bf(tile[kl][jj + jl0]);
    } else {                               // prep_Wcat: 3072 blocks
        int idx = (bid - 896) * 256 + t;
        int n = idx / NW, j = idx - n * NW;
        float v = (j < 128) ? ow1[(size_t)n * 128 + j] : cw1[(size_t)n * 64 + (j - 128)];
        Wcat[idx] = f2bf(v);
    }
}

// ============ L2: colmean_fin + Gram split-K (merged) ============
__global__ __launch_bounds__(256) void fin_gram_k(const float* __restrict__ epart,
        const unsigned short* __restrict__ WT, float* __restrict__ e,
        float* __restrict__ Gpart) {
    __shared__ __align__(16) unsigned short As[64][72];
    __shared__ __align__(16) unsigned short Bs[64][72];
    const int bid = blockIdx.x, t = threadIdx.x;
    if (bid < 16) {                        // colmean finalize
        int col = bid * 256 + t;
        float s = 0.f;
        #pragma unroll
        for (int z = 0; z < 32; ++z) s += epart[(size_t)z * PDIM + col];
        e[col] = s * (1.0f / 1024.0f);
        return;
    }
    int g = bid - 16;                      // 72 blocks: Gram = WT @ WT^T (split-K 8)
    const int kz = g & 7; g >>= 3;
    const int m0 = (g % 3) * 64, n0 = (g / 3) * 64;
    const int w = t >> 6, l = t & 63;
    const int lr = l & 15, lk = (l >> 4) * 8;
    f32x4 acc[4];
    #pragma unroll
    for (int nf = 0; nf < 4; ++nf) acc[nf] = (f32x4){0.f, 0.f, 0.f, 0.f};
    for (int kt = 0; kt < 512; kt += 64) {
        const int kbase = kz * 512 + kt;
        #pragma unroll
        for (int c = 0; c < 2; ++c) {
            int ch = t + c * 256;
            int row = ch >> 3, col8 = (ch & 7) * 8;
            *reinterpret_cast<float4*>(&As[row][col8]) =
                *reinterpret_cast<const float4*>(WT + (size_t)(m0 + row) * PDIM + kbase + col8);
            *reinterpret_cast<float4*>(&Bs[row][col8]) =
                *reinterpret_cast<const float4*>(WT + (size_t)(n0 + row) * PDIM + kbase + col8);
        }
        __syncthreads();
        #pragma unroll
        for (int h = 0; h < 2; ++h) {
            bf16x8 a = *reinterpret_cast<const bf16x8*>(&As[w * 16 + lr][h * 32 + lk]);
            #pragma unroll
            for (int nf = 0; nf < 4; ++nf) {
                bf16x8 b = *reinterpret_cast<const bf16x8*>(&Bs[nf * 16 + lr][h * 32 + lk]);
                acc[nf] = __builtin_amdgcn_mfma_f32_16x16x32_bf16(a, b, acc[nf], 0, 0, 0);
            }
        }
        __syncthreads();
    }
    float* op = Gpart + (size_t)kz * NW * NW + (size_t)(m0 + w * 16 + (l >> 4) * 4) * NW + n0;
    #pragma unroll
    for (int nf = 0; nf < 4; ++nf)
        #pragma unroll
        for (int r = 0; r < 4; ++r)
            op[(size_t)r * NW + nf * 16 + lr] = acc[nf][r];
}

// ============ L3: T = tanh(0.7e+0.3enc) @ Wf  (N=192 per block, split-K 8) ============
//             + 144 extra blocks reduce Gpart -> Gram (bf16)
__global__ __launch_bounds__(256) void gemmT_k(const float* __restrict__ tp,
        const float* __restrict__ cons, const float* __restrict__ e,
        const unsigned short* __restrict__ WT, float* __restrict__ parts,
        const float* __restrict__ Gpart, unsigned short* __restrict__ Gram) {
    __shared__ __align__(16) unsigned short As[64][72];
    __shared__ __align__(16) unsigned short Bs[NW][72];
    const int bid = blockIdx.x, t = threadIdx.x;
    if (bid >= 256) {                      // Gram reduce
        int idx = (bid - 256) * 256 + t;   // 144*256 = 36864
        float s = 0.f;
        #pragma unroll
        for (int z = 0; z < 8; ++z) s += Gpart[(size_t)z * NW * NW + idx];
        Gram[idx] = f2bf(s);
        return;
    }
    const int m0 = (bid >> 3) * 64;
    const int kz = bid & 7;
    const int w = t >> 6, l = t & 63;
    const int lr = l & 15, lk = (l >> 4) * 8;

    f32x4 acc[12];
    #pragma unroll
    for (int nf = 0; nf < 12; ++nf) acc[nf] = (f32x4){0.f, 0.f, 0.f, 0.f};

    const int colA = t & 63, rowA0 = t >> 6;
    for (int kt = 0; kt < 512; kt += 64) {
        const int kbase = kz * 512 + kt;
        // A staging: params0 computed on the fly (tanh), never materialized
        const int k = kbase + colA;
        const float ek = e[k];
        #pragma unroll
        for (int c = 0; c < 16; ++c) {
            int row = rowA0 + c * 4;
            int m = m0 + row;
            float encv = (k < PAR) ? tp[(size_t)m * PAR + k] : cons[m * CONS + (k - PAR)];
            As[row][colA] = f2bf(fast_tanh(0.7f * ek + 0.3f * encv));
        }
        #pragma unroll
        for (int c = 0; c < 6; ++c) {      // B staging: 192x64 bf16
            int ch = t + c * 256;
            int row = ch >> 3, col8 = (ch & 7) * 8;
            *reinterpret_cast<float4*>(&Bs[row][col8]) =
                *reinterpret_cast<const float4*>(WT + (size_t)row * PDIM + kbase + col8);
        }
        __syncthreads();
        #pragma unroll
        for (int h = 0; h < 2; ++h) {
            bf16x8 a = *reinterpret_cast<const bf16x8*>(&As[w * 16 + lr][h * 32 + lk]);
            #pragma unroll
            for (int nf = 0; nf < 12; ++nf) {
                bf16x8 b = *reinterpret_cast<const bf16x8*>(&Bs[nf * 16 + lr][h * 32 + lk]);
                acc[nf] = __builtin_amdgcn_mfma_f32_16x16x32_bf16(a, b, acc[nf], 0, 0, 0);
            }
        }
        __syncthreads();
    }
    float* op = parts + (size_t)kz * BATCH * NW + (size_t)(m0 + w * 16 + (l >> 4) * 4) * NW;
    #pragma unroll
    for (int nf = 0; nf < 12; ++nf)
        #pragma unroll
        for (int r = 0; r < 4; ++r)
            op[(size_t)r * NW + nf * 16 + lr] = acc[nf][r];
}

// ============ L4: fused 3-step refinement (row-local via Gram) ============
__global__ __launch_bounds__(128) void refine_k(const float* __restrict__ Tparts,
        const float* __restrict__ cb1, const float* __restrict__ cw2,
        const float* __restrict__ cb2, const float* __restrict__ ow1,
        const float* __restrict__ ob1, const float* __restrict__ ow2,
        const float* __restrict__ ob2, const float* __restrict__ ow3,
        const unsigned short* __restrict__ Gram, unsigned short* __restrict__ Dsbf) {
    const int b = blockIdx.x, t = threadIdx.x;
    __shared__ float Ts[NW], dsum[NW], drot[NW];
    __shared__ float hc[64], cv[16], h1[128], dh2[64], dh1s[128], dz2[16];
    __shared__ unsigned short ow2s[128 * 65];   // 65-pad: 2-way (free) banks both ways

    for (int i = t; i < 8192; i += 128) {
        int j = i >> 6, k = i & 63;
        ow2s[j * 65 + k] = f2bf(ow2[i]);
    }
    {   // Ts = sum_z Tparts[z][b][:]
        float s = 0.f;
        #pragma unroll
        for (int z = 0; z < 8; ++z) s += Tparts[(size_t)z * BATCH * NW + (size_t)b * NW + t];
        Ts[t] = s; dsum[t] = 0.f;
        if (t < 64) {
            s = 0.f;
            #pragma unroll
            for (int z = 0; z < 8; ++z) s += Tparts[(size_t)z * BATCH * NW + (size_t)b * NW + 128 + t];
            Ts[128 + t] = s; dsum[128 + t] = 0.f;
        }
    }
    __syncthreads();

    for (int step = 0; step < 3; ++step) {
        if (t < 64) hc[t] = fmaxf(Ts[t] + cb1[t], 0.f);
        __syncthreads();
        if (t < 10) {
            float s = cb2[t];
            for (int k = 0; k < 64; ++k) s += hc[k] * cw2[k * 10 + t];
            cv[t] = 1.f / (1.f + __expf(-s));
        }
        __syncthreads();
        {
            float s = Ts[64 + t] + ob1[t];
            #pragma unroll
            for (int c = 0; c < 10; ++c) s += cv[c] * ow1[(size_t)(4096 + c) * 128 + t];
            h1[t] = fmaxf(s, 0.f);
        }
        __syncthreads();
        if (t < 64) {
            float s = ob2[t];
            for (int j = 0; j < 128; ++j) s += h1[j] * bf2f(ow2s[j * 65 + t]);
            dh2[t] = (s > 0.f) ? ow3[t] : 0.f;
        }
        __syncthreads();
        {
            float s = 0.f;
            for (int l = 0; l < 64; ++l) s += dh2[l] * bf2f(ow2s[t * 65 + l]);
            float v = (h1[t] > 0.f) ? s : 0.f;
            dh1s[t] = v; dsum[t] += v; drot[64 + t] = v;
        }
        __syncthreads();
        if (t < 10) {
            float s = 0.f;
            for (int j = 0; j < 128; ++j) s += dh1s[j] * ow1[(size_t)(4096 + t) * 128 + j];
            float c = cv[t];
            dz2[t] = s * c * (1.f - c);
        }
        __syncthreads();
        if (t < 64) {
            float s = 0.f;
            #pragma unroll
            for (int c = 0; c < 10; ++c) s += dz2[c] * cw2[t * 10 + c];
            float w2 = (hc[t] > 0.f) ? s : 0.f;
            dsum[128 + t] += w2; drot[t] = w2;
        }
        __syncthreads();
        if (step < 2) {  // row-local T-update: Ts[j] -= 0.01 * <Gram row j, drot>
            {
                float u = 0.f;
                const unsigned short* gr = Gram + (size_t)t * NW;
                #pragma unroll 4
                for (int k8 = 0; k8 < 24; ++k8) {
                    ushort8 gv = *reinterpret_cast<const ushort8*>(gr + k8 * 8);
                    float4 d0 = *reinterpret_cast<const float4*>(&drot[k8 * 8]);
                    float4 d1 = *reinterpret_cast<const float4*>(&drot[k8 * 8 + 4]);
                    u += bf2f(gv[0]) * d0.x + bf2f(gv[1]) * d0.y + bf2f(gv[2]) * d0.z + bf2f(gv[3]) * d0.w
                       + bf2f(gv[4]) * d1.x + bf2f(gv[5]) * d1.y + bf2f(gv[6]) * d1.z + bf2f(gv[7]) * d1.w;
                }
                Ts[t] -= 0.01f * u;
            }
            if (t < 64) {
                float u = 0.f;
                const unsigned short* gr = Gram + (size_t)(128 + t) * NW;
                #pragma unroll 4
                for (int k8 = 0; k8 < 24; ++k8) {
                    ushort8 gv = *reinterpret_cast<const ushort8*>(gr + k8 * 8);
                    float4 d0 = *reinterpret_cast<const float4*>(&drot[k8 * 8]);
                    float4 d1 = *reinterpret_cast<const float4*>(&drot[k8 * 8 + 4]);
                    u += bf2f(gv[0]) * d0.x + bf2f(gv[1]) * d0.y + bf2f(gv[2]) * d0.z + bf2f(gv[3]) * d0.w
                       + bf2f(gv[4]) * d1.x + bf2f(gv[5]) * d1.y + bf2f(gv[6]) * d1.z + bf2f(gv[7]) * d1.w;
                }
                Ts[128 + t] -= 0.01f * u;
            }
            __syncthreads();
        }
    }
    Dsbf[(size_t)b * NW + t] = f2bf(dsum[t]);
    if (t < 64) Dsbf[(size_t)b * NW + 128 + t] = f2bf(dsum[128 + t]);
}

// ============ L5: pm = tanh(0.7e+0.3enc) - 0.01 * Dsum @ Wcat^T ============
__global__ __launch_bounds__(256) void final_k(const unsigned short* __restrict__ Dsbf,
        const unsigned short* __restrict__ Wcat, const float* __restrict__ tp,
        const float* __restrict__ cons, const float* __restrict__ e,
        float* __restrict__ pm) {
    __shared__ __align__(16) unsigned short As[64][72];
    __shared__ __align__(16) unsigned short Bs[256][72];
    const int bid = blockIdx.x, t = threadIdx.x;
    const int m0 = (bid >> 4) * 64;
    const int n0 = (bid & 15) * 256;
    const int w = t >> 6, l = t & 63;
    const int lr = l & 15, lk = (l >> 4) * 8;

    f32x4 acc[16];
    #pragma unroll
    for (int nf = 0; nf < 16; ++nf) acc[nf] = (f32x4){0.f, 0.f, 0.f, 0.f};

    for (int kt = 0; kt < NW; kt += 64) {
        #pragma unroll
        for (int c = 0; c < 2; ++c) {      // A: Dsbf 64x64
            int ch = t + c * 256;
            int row = ch >> 3, col8 = (ch & 7) * 8;
            *reinterpret_cast<float4*>(&As[row][col8]) =
                *reinterpret_cast<const float4*>(Dsbf + (size_t)(m0 + row) * NW + kt + col8);
        }
        #pragma unroll
        for (int c = 0; c < 8; ++c) {      // B: Wcat 256x64
            int ch = t + c * 256;
            int row = ch >> 3, col8 = (ch & 7) * 8;
            *reinterpret_cast<float4*>(&Bs[row][col8]) =
                *reinterpret_cast<const float4*>(Wcat + (size_t)(n0 + row) * NW + kt + col8);
        }
        __syncthreads();
        #pragma unroll
        for (int h = 0; h < 2; ++h) {
            bf16x8 a = *reinterpret_cast<const bf16x8*>(&As[w * 16 + lr][h * 32 + lk]);
            #pragma unroll
            for (int nf = 0; nf < 16; ++nf) {
                bf16x8 b = *reinterpret_cast<const bf16x8*>(&Bs[nf * 16 + lr][h * 32 + lk]);
                acc[nf] = __builtin_amdgcn_mfma_f32_16x16x32_bf16(a, b, acc[nf], 0, 0, 0);
            }
        }
        __syncthreads();
    }
    const int mrow = m0 + w * 16 + (l >> 4) * 4;
    #pragma unroll
    for (int nf = 0; nf < 16; ++nf) {
        int n = n0 + nf * 16 + lr;
        float ek = e[n];
        #pragma unroll
        for (int r = 0; r < 4; ++r) {
            int m = mrow + r;
            float encv = (n < PAR) ? tp[(size_t)m * PAR + n] : cons[m * CONS + (n - PAR)];
            pm[(size_t)m * PDIM + n] = fast_tanh(0.7f * ek + 0.3f * encv) - 0.01f * acc[nf][r];
        }
    }
}

extern "C" void kernel_launch(void* const* d_in, const int* in_sizes, int n_in,
                              void* d_out, int out_size, void* d_ws, size_t ws_size,
                              hipStream_t stream) {
    const float* tp   = (const float*)d_in[0];
    const float* cons = (const float*)d_in[1];
    // d_in[2] transverse_field, d_in[3] coupling: DEAD CODE (annealing is identity)
    const float* mp   = (const float*)d_in[4];
    const float* cw1  = (const float*)d_in[5];
    const float* cb1  = (const float*)d_in[6];
    const float* cw2  = (const float*)d_in[7];
    const float* cb2  = (const float*)d_in[8];
    const float* ow1  = (const float*)d_in[9];
    const float* ob1  = (const float*)d_in[10];
    const float* ow2  = (const float*)d_in[11];
    const float* ob2  = (const float*)d_in[12];
    const float* ow3  = (const float*)d_in[13];
    float* pm = (float*)d_out;

    float* f = (float*)d_ws;
    float* e      = f;  f += 4096;
    float* epart  = f;  f += 32 * 4096;
    float* Gpart  = f;  f += 8 * NW * NW;
    float* Tparts = f;  f += 8 * BATCH * NW;
    unsigned short* u = (unsigned short*)f;
    unsigned short* WT   = u;  u += NW * PDIM;
    unsigned short* Wcat = u;  u += PDIM * NW;
    unsigned short* Gram = u;  u += NW * NW;
    unsigned short* Dsbf = u;

    prep_all_k<<<3968, 256, 0, stream>>>(mp, cw1, ow1, epart, WT, Wcat);
    fin_gram_k<<<88, 256, 0, stream>>>(epart, WT, e, Gpart);
    gemmT_k<<<400, 256, 0, stream>>>(tp, cons, e, WT, Tparts, Gpart, Gram);
    refine_k<<<BATCH, 128, 0, stream>>>(Tparts, cb1, cw2, cb2, ow1, ob1, ow2, ob2, ow3,
                                        Gram, Dsbf);
    final_k<<<512, 256, 0, stream>>>(Dsbf, Wcat, tp, cons, e, pm);
}

// Round 4
// 138.508 us; speedup vs baseline: 1.3310x; 1.3310x over previous
//
#include <hip/hip_runtime.h>
#include <math.h>

#define BATCH 2048
#define PDIM  4096
#define PAR   4086
#define CONS  10
#define NW    192     // 64 (cw1 cols) + 128 (ow1 cols)

typedef __attribute__((ext_vector_type(8))) short bf16x8;
typedef __attribute__((ext_vector_type(8))) unsigned short ushort8;
typedef __attribute__((ext_vector_type(4))) float f32x4;

__device__ __forceinline__ unsigned short f2bf(float f) {
    unsigned int u = __float_as_uint(f);
    u += 0x7FFFu + ((u >> 16) & 1u);      // RTNE
    return (unsigned short)(u >> 16);
}
__device__ __forceinline__ float bf2f(unsigned short u) {
    return __uint_as_float(((unsigned int)u) << 16);
}
__device__ __forceinline__ float fast_tanh(float z) {
    float a = fabsf(z);
    float ex = __expf(-2.f * a);                       // e^-2a
    float th = (1.f - ex) * __builtin_amdgcn_rcpf(1.f + ex);
    return copysignf(th, z);
}

// ============ L1: colmean_part + prep_WT + prep_Wcat (merged) ============
__global__ __launch_bounds__(256) void prep_all_k(const float* __restrict__ mp,
        const float* __restrict__ cw1, const float* __restrict__ ow1,
        float* __restrict__ epart, unsigned short* __restrict__ WT,
        unsigned short* __restrict__ Wcat) {
    __shared__ float tile[64][33];
    const int bid = blockIdx.x, t = threadIdx.x;
    if (bid < 512) {                       // colmean partial: 16 x 32
        int col = (bid & 15) * 256 + t;
        int z = bid >> 4;
        float s = 0.f;
        int r0 = z * 32;
        for (int r = 0; r < 32; ++r) s += mp[(size_t)(r0 + r) * PDIM + col];
        epart[(size_t)z * PDIM + col] = s;
    } else if (bid < 896) {                // prep_WT: 64 k-chunks x 6 j-chunks
        int g = bid - 512;
        int k0 = (g & 63) * 64, j0 = (g >> 6) * 32;
        const float* src; int lds_, jb;
        if (j0 < 64) { src = cw1; lds_ = 64;  jb = j0; }
        else         { src = ow1; lds_ = 128; jb = j0 - 64; }
        int jl = t & 31, kl0 = t >> 5;
        for (int kk = 0; kk < 64; kk += 8)
            tile[kk + kl0][jl] = src[(size_t)(k0 + kk + kl0) * lds_ + jb + jl];
        __syncthreads();
        int kl = t & 63, jl0 = t >> 6;
        for (int jj = 0; jj < 32; jj += 4)
            WT[(size_t)(j0 + jj + jl0) * PDIM + k0 + kl] = f2bf(tile[kl][jj + jl0]);
    } else {                               // prep_Wcat: 3072 blocks
        int idx = (bid - 896) * 256 + t;
        int n = idx / NW, j = idx - n * NW;
        float v = (j < 128) ? ow1[(size_t)n * 128 + j] : cw1[(size_t)n * 64 + (j - 128)];
        Wcat[idx] = f2bf(v);
    }
}

// ============ L2: colmean_fin + Gram split-K (merged) ============
__global__ __launch_bounds__(256) void fin_gram_k(const float* __restrict__ epart,
        const unsigned short* __restrict__ WT, float* __restrict__ e,
        float* __restrict__ Gpart) {
    __shared__ __align__(16) unsigned short As[64][72];
    __shared__ __align__(16) unsigned short Bs[64][72];
    const int bid = blockIdx.x, t = threadIdx.x;
    if (bid < 16) {                        // colmean finalize
        int col = bid * 256 + t;
        float s = 0.f;
        #pragma unroll
        for (int z = 0; z < 32; ++z) s += epart[(size_t)z * PDIM + col];
        e[col] = s * (1.0f / 1024.0f);
        return;
    }
    int g = bid - 16;                      // 72 blocks: Gram = WT @ WT^T (split-K 8)
    const int kz = g & 7; g >>= 3;
    const int m0 = (g % 3) * 64, n0 = (g / 3) * 64;
    const int w = t >> 6, l = t & 63;
    const int lr = l & 15, lk = (l >> 4) * 8;
    f32x4 acc[4];
    #pragma unroll
    for (int nf = 0; nf < 4; ++nf) acc[nf] = (f32x4){0.f, 0.f, 0.f, 0.f};
    for (int kt = 0; kt < 512; kt += 64) {
        const int kbase = kz * 512 + kt;
        #pragma unroll
        for (int c = 0; c < 2; ++c) {
            int ch = t + c * 256;
            int row = ch >> 3, col8 = (ch & 7) * 8;
            *reinterpret_cast<float4*>(&As[row][col8]) =
                *reinterpret_cast<const float4*>(WT + (size_t)(m0 + row) * PDIM + kbase + col8);
            *reinterpret_cast<float4*>(&Bs[row][col8]) =
                *reinterpret_cast<const float4*>(WT + (size_t)(n0 + row) * PDIM + kbase + col8);
        }
        __syncthreads();
        #pragma unroll
        for (int h = 0; h < 2; ++h) {
            bf16x8 a = *reinterpret_cast<const bf16x8*>(&As[w * 16 + lr][h * 32 + lk]);
            #pragma unroll
            for (int nf = 0; nf < 4; ++nf) {
                bf16x8 b = *reinterpret_cast<const bf16x8*>(&Bs[nf * 16 + lr][h * 32 + lk]);
                acc[nf] = __builtin_amdgcn_mfma_f32_16x16x32_bf16(a, b, acc[nf], 0, 0, 0);
            }
        }
        __syncthreads();
    }
    float* op = Gpart + (size_t)kz * NW * NW + (size_t)(m0 + w * 16 + (l >> 4) * 4) * NW + n0;
    #pragma unroll
    for (int nf = 0; nf < 4; ++nf)
        #pragma unroll
        for (int r = 0; r < 4; ++r)
            op[(size_t)r * NW + nf * 16 + lr] = acc[nf][r];
}

// ============ L3: T = tanh(0.7e+0.3enc) @ Wf  (N=192 per block, split-K 8) ============
//             + 144 extra blocks reduce Gpart -> Gram (bf16)
__global__ __launch_bounds__(256) void gemmT_k(const float* __restrict__ tp,
        const float* __restrict__ cons, const float* __restrict__ e,
        const unsigned short* __restrict__ WT, float* __restrict__ parts,
        const float* __restrict__ Gpart, unsigned short* __restrict__ Gram) {
    __shared__ __align__(16) unsigned short As[64][72];
    __shared__ __align__(16) unsigned short Bs[NW][72];
    const int bid = blockIdx.x, t = threadIdx.x;
    if (bid >= 256) {                      // Gram reduce
        int idx = (bid - 256) * 256 + t;   // 144*256 = 36864
        float s = 0.f;
        #pragma unroll
        for (int z = 0; z < 8; ++z) s += Gpart[(size_t)z * NW * NW + idx];
        Gram[idx] = f2bf(s);
        return;
    }
    const int m0 = (bid >> 3) * 64;
    const int kz = bid & 7;
    const int w = t >> 6, l = t & 63;
    const int lr = l & 15, lk = (l >> 4) * 8;

    f32x4 acc[12];
    #pragma unroll
    for (int nf = 0; nf < 12; ++nf) acc[nf] = (f32x4){0.f, 0.f, 0.f, 0.f};

    const int colA = t & 63, rowA0 = t >> 6;
    for (int kt = 0; kt < 512; kt += 64) {
        const int kbase = kz * 512 + kt;
        // A staging: params0 computed on the fly (tanh), never materialized
        const int k = kbase + colA;
        const float ek = e[k];
        #pragma unroll
        for (int c = 0; c < 16; ++c) {
            int row = rowA0 + c * 4;
            int m = m0 + row;
            float encv = (k < PAR) ? tp[(size_t)m * PAR + k] : cons[m * CONS + (k - PAR)];
            As[row][colA] = f2bf(fast_tanh(0.7f * ek + 0.3f * encv));
        }
        #pragma unroll
        for (int c = 0; c < 6; ++c) {      // B staging: 192x64 bf16
            int ch = t + c * 256;
            int row = ch >> 3, col8 = (ch & 7) * 8;
            *reinterpret_cast<float4*>(&Bs[row][col8]) =
                *reinterpret_cast<const float4*>(WT + (size_t)row * PDIM + kbase + col8);
        }
        __syncthreads();
        #pragma unroll
        for (int h = 0; h < 2; ++h) {
            bf16x8 a = *reinterpret_cast<const bf16x8*>(&As[w * 16 + lr][h * 32 + lk]);
            #pragma unroll
            for (int nf = 0; nf < 12; ++nf) {
                bf16x8 b = *reinterpret_cast<const bf16x8*>(&Bs[nf * 16 + lr][h * 32 + lk]);
                acc[nf] = __builtin_amdgcn_mfma_f32_16x16x32_bf16(a, b, acc[nf], 0, 0, 0);
            }
        }
        __syncthreads();
    }
    float* op = parts + (size_t)kz * BATCH * NW + (size_t)(m0 + w * 16 + (l >> 4) * 4) * NW;
    #pragma unroll
    for (int nf = 0; nf < 12; ++nf)
        #pragma unroll
        for (int r = 0; r < 4; ++r)
            op[(size_t)r * NW + nf * 16 + lr] = acc[nf][r];
}

// ============ L4: fused 3-step refinement — MFMA, 1 wave = 16 batch rows ============
// Stages per step (all MFMA 16x16x32 bf16, per-wave LDS tiles between stages):
//  hc=relu(T[:,:64]+cb1) -> cv=sigm(hc@cw2) -> h1=relu(T[:,64:]+ob1+cv@ow1c)
//  -> dh2=(h1@ow2+ob2>0)?ow3:0 -> dh1=(h1>0)*(dh2@ow2^T) -> dz2=(dh1@ow1c^T)*cv'
//  -> dhc=(hc>0)*(dz2@cw2^T) -> T -= 0.01*[dhc|dh1]@Gram (Gram read from L2)
__global__ __launch_bounds__(64) void refine_k(const float* __restrict__ Tparts,
        const float* __restrict__ cb1, const float* __restrict__ cw2,
        const float* __restrict__ cb2, const float* __restrict__ ow1,
        const float* __restrict__ ob1, const float* __restrict__ ow2,
        const float* __restrict__ ob2, const float* __restrict__ ow3,
        const unsigned short* __restrict__ Gram, unsigned short* __restrict__ Dsbf) {
    __shared__ __align__(16) float Ts[16][196];
    __shared__ __align__(16) unsigned short hcB[16][72];
    __shared__ __align__(16) unsigned short h1B[16][136];
    __shared__ __align__(16) unsigned short dh2B[16][72];
    __shared__ __align__(16) unsigned short dh1B[16][136];
    __shared__ __align__(16) unsigned short dhcB[16][72];
    __shared__ __align__(16) unsigned short cvA[16][40];
    __shared__ __align__(16) unsigned short dz2A[16][40];
    __shared__ __align__(16) unsigned short cw2B[16][72];    // B[n][k]=cw2[k][n], n<10
    __shared__ __align__(16) unsigned short ow1cB[128][40];  // B[n][k]=ow1[4096+k][n], k<10
    __shared__ __align__(16) unsigned short ow2B[64][136];   // B[n][k]=ow2[k][n]
    __shared__ __align__(16) unsigned short ow2TB[128][72];  // B[n][k]=ow2[n][k]
    __shared__ __align__(16) unsigned short ow1cTB[16][136]; // B[n][k]=ow1[4096+n][k], n<10
    __shared__ __align__(16) unsigned short cw2TB[64][40];   // B[n][k]=cw2[n][k], k<10
    __shared__ float cb1f[64], ob1f[128], ob2f[64], cb2f[16], ow3f[64];

    const int t = threadIdx.x;
    const int b16 = blockIdx.x * 16;
    const int lr = t & 15, lq = t >> 4, lk = lq * 8;

    // ---- biases ----
    cb1f[t] = cb1[t]; ob2f[t] = ob2[t]; ow3f[t] = ow3[t];
    ob1f[t] = ob1[t]; ob1f[64 + t] = ob1[64 + t];
    if (t < 16) cb2f[t] = (t < 10) ? cb2[t] : 0.f;
    // ---- zero-init padded tiles (avoid NaN garbage) ----
    for (int i = t; i < 16 * 72;  i += 64) (&cw2B[0][0])[i] = 0;
    for (int i = t; i < 128 * 40; i += 64) (&ow1cB[0][0])[i] = 0;
    for (int i = t; i < 16 * 136; i += 64) (&ow1cTB[0][0])[i] = 0;
    for (int i = t; i < 64 * 40;  i += 64) (&cw2TB[0][0])[i] = 0;
    for (int i = t; i < 16 * 40;  i += 64) { (&cvA[0][0])[i] = 0; (&dz2A[0][0])[i] = 0; }
    __syncthreads();
    // ---- weight tiles ----
    #pragma unroll
    for (int n = 0; n < 10; ++n) cw2B[n][t] = f2bf(cw2[t * 10 + n]);
    for (int g = t; g < 1280; g += 64) { int n = g & 127, k = g >> 7;
        ow1cB[n][k] = f2bf(ow1[(size_t)(4096 + k) * 128 + n]); }
    for (int k = 0; k < 128; ++k) ow2B[t][k] = f2bf(ow2[k * 64 + t]);
    for (int i = t; i < 2048; i += 64) { int n = i >> 4, c4 = (i & 15) * 4;
        float4 v = *reinterpret_cast<const float4*>(ow2 + n * 64 + c4);
        unsigned int p0 = (unsigned int)f2bf(v.x) | ((unsigned int)f2bf(v.y) << 16);
        unsigned int p1 = (unsigned int)f2bf(v.z) | ((unsigned int)f2bf(v.w) << 16);
        *reinterpret_cast<uint2*>(&ow2TB[n][c4]) = make_uint2(p0, p1); }
    for (int i = t; i < 320; i += 64) { int n = i >> 5, c4 = (i & 31) * 4;
        float4 v = *reinterpret_cast<const float4*>(ow1 + (size_t)(4096 + n) * 128 + c4);
        unsigned int p0 = (unsigned int)f2bf(v.x) | ((unsigned int)f2bf(v.y) << 16);
        unsigned int p1 = (unsigned int)f2bf(v.z) | ((unsigned int)f2bf(v.w) << 16);
        *reinterpret_cast<uint2*>(&ow1cTB[n][c4]) = make_uint2(p0, p1); }
    for (int g = t; g < 640; g += 64) { int n = g / 10, k = g - n * 10;
        cw2TB[n][k] = f2bf(cw2[n * 10 + k]); }
    // ---- Ts = sum_z Tparts[z][rows][:] ----
    for (int i = t; i < 768; i += 64) {
        int row = i / 48, c4 = (i - row * 48) * 4;
        const float* src = Tparts + (size_t)(b16 + row) * NW + c4;
        float4 s = make_float4(0.f, 0.f, 0.f, 0.f);
        #pragma unroll
        for (int z = 0; z < 8; ++z) {
            float4 v = *reinterpret_cast<const float4*>(src + (size_t)z * BATCH * NW);
            s.x += v.x; s.y += v.y; s.z += v.z; s.w += v.w;
        }
        *reinterpret_cast<float4*>(&Ts[row][c4]) = s;
    }
    __syncthreads();

    f32x4 ds1[8], ds2[4];
    #pragma unroll
    for (int nf = 0; nf < 8; ++nf) ds1[nf] = (f32x4){0.f, 0.f, 0.f, 0.f};
    #pragma unroll
    for (int nf = 0; nf < 4; ++nf) ds2[nf] = (f32x4){0.f, 0.f, 0.f, 0.f};
    float sv[4];

    for (int step = 0; step < 3; ++step) {
        // (1) hc
        for (int i = t; i < 1024; i += 64) { int row = i >> 6, k = i & 63;
            hcB[row][k] = f2bf(fmaxf(Ts[row][k] + cb1f[k], 0.f)); }
        __syncthreads();
        // (2) cv = sigmoid(hc @ cw2)
        f32x4 accv = (f32x4){0.f, 0.f, 0.f, 0.f};
        #pragma unroll
        for (int h = 0; h < 2; ++h) {
            bf16x8 a = *reinterpret_cast<const bf16x8*>(&hcB[lr][h * 32 + lk]);
            bf16x8 bb = *reinterpret_cast<const bf16x8*>(&cw2B[lr][h * 32 + lk]);
            accv = __builtin_amdgcn_mfma_f32_16x16x32_bf16(a, bb, accv, 0, 0, 0);
        }
        #pragma unroll
        for (int r = 0; r < 4; ++r) {
            float c = 1.f / (1.f + __expf(-(accv[r] + cb2f[lr])));
            sv[r] = c * (1.f - c);
            cvA[lq * 4 + r][lr] = f2bf(c);
        }
        __syncthreads();
        // (3) h1 = relu(T[:,64:] + ob1 + cv @ ow1c)
        {
            bf16x8 a = *reinterpret_cast<const bf16x8*>(&cvA[lr][lk]);
            f32x4 acch[8];
            #pragma unroll
            for (int nf = 0; nf < 8; ++nf) {
                bf16x8 bb = *reinterpret_cast<const bf16x8*>(&ow1cB[nf * 16 + lr][lk]);
                acch[nf] = __builtin_amdgcn_mfma_f32_16x16x32_bf16(a, bb,
                            (f32x4){0.f, 0.f, 0.f, 0.f}, 0, 0, 0);
            }
            #pragma unroll
            for (int nf = 0; nf < 8; ++nf)
                #pragma unroll
                for (int r = 0; r < 4; ++r) {
                    int row = lq * 4 + r, col = nf * 16 + lr;
                    float v = acch[nf][r] + Ts[row][64 + col] + ob1f[col];
                    h1B[row][col] = f2bf(fmaxf(v, 0.f));
                }
        }
        __syncthreads();
        // (4) dh2 = (h1@ow2+ob2 > 0) ? ow3 : 0
        {
            f32x4 accz[4];
            #pragma unroll
            for (int nf = 0; nf < 4; ++nf) accz[nf] = (f32x4){0.f, 0.f, 0.f, 0.f};
            #pragma unroll
            for (int kc = 0; kc < 4; ++kc) {
                bf16x8 a = *reinterpret_cast<const bf16x8*>(&h1B[lr][kc * 32 + lk]);
                #pragma unroll
                for (int nf = 0; nf < 4; ++nf) {
                    bf16x8 bb = *reinterpret_cast<const bf16x8*>(&ow2B[nf * 16 + lr][kc * 32 + lk]);
                    accz[nf] = __builtin_amdgcn_mfma_f32_16x16x32_bf16(a, bb, accz[nf], 0, 0, 0);
                }
            }
            #pragma unroll
            for (int nf = 0; nf < 4; ++nf)
                #pragma unroll
                for (int r = 0; r < 4; ++r) {
                    int col = nf * 16 + lr;
                    float z = accz[nf][r] + ob2f[col];
                    dh2B[lq * 4 + r][col] = f2bf((z > 0.f) ? ow3f[col] : 0.f);
                }
        }
        __syncthreads();
        // (5) dh1 = (h1>0) * (dh2 @ ow2^T)
        {
            f32x4 accd[8];
            #pragma unroll
            for (int nf = 0; nf < 8; ++nf) accd[nf] = (f32x4){0.f, 0.f, 0.f, 0.f};
            #pragma unroll
            for (int kc = 0; kc < 2; ++kc) {
                bf16x8 a = *reinterpret_cast<const bf16x8*>(&dh2B[lr][kc * 32 + lk]);
                #pragma unroll
                for (int nf = 0; nf < 8; ++nf) {
                    bf16x8 bb = *reinterpret_cast<const bf16x8*>(&ow2TB[nf * 16 + lr][kc * 32 + lk]);
                    accd[nf] = __builtin_amdgcn_mfma_f32_16x16x32_bf16(a, bb, accd[nf], 0, 0, 0);
                }
            }
            #pragma unroll
            for (int nf = 0; nf < 8; ++nf)
                #pragma unroll
                for (int r = 0; r < 4; ++r) {
                    int row = lq * 4 + r, col = nf * 16 + lr;
                    float v = (bf2f(h1B[row][col]) > 0.f) ? accd[nf][r] : 0.f;
                    ds1[nf][r] += v;
                    dh1B[row][col] = f2bf(v);
                }
        }
        __syncthreads();
        // (6) dz2 = (dh1 @ ow1c^T) * cv*(1-cv)
        {
            f32x4 accq = (f32x4){0.f, 0.f, 0.f, 0.f};
            #pragma unroll
            for (int kc = 0; kc < 4; ++kc) {
                bf16x8 a = *reinterpret_cast<const bf16x8*>(&dh1B[lr][kc * 32 + lk]);
                bf16x8 bb = *reinterpret_cast<const bf16x8*>(&ow1cTB[lr][kc * 32 + lk]);
                accq = __builtin_amdgcn_mfma_f32_16x16x32_bf16(a, bb, accq, 0, 0, 0);
            }
            #pragma unroll
            for (int r = 0; r < 4; ++r)
                dz2A[lq * 4 + r][lr] = f2bf(accq[r] * sv[r]);
        }
        __syncthreads();
        // (7) dhc = (hc>0) * (dz2 @ cw2^T)
        {
            bf16x8 a = *reinterpret_cast<const bf16x8*>(&dz2A[lr][lk]);
            f32x4 accc[4];
            #pragma unroll
            for (int nf = 0; nf < 4; ++nf) {
                bf16x8 bb = *reinterpret_cast<const bf16x8*>(&cw2TB[nf * 16 + lr][lk]);
                accc[nf] = __builtin_amdgcn_mfma_f32_16x16x32_bf16(a, bb,
                            (f32x4){0.f, 0.f, 0.f, 0.f}, 0, 0, 0);
            }
            #pragma unroll
            for (int nf = 0; nf < 4; ++nf)
                #pragma unroll
                for (int r = 0; r < 4; ++r) {
                    int row = lq * 4 + r, col = nf * 16 + lr;
                    float v = (bf2f(hcB[row][col]) > 0.f) ? accc[nf][r] : 0.f;
                    ds2[nf][r] += v;
                    dhcB[row][col] = f2bf(v);
                }
        }
        __syncthreads();
        // (8) T -= 0.01 * [dhc | dh1] @ Gram   (Gram symmetric bf16, from L2)
        if (step < 2) {
            f32x4 accT[12];
            #pragma unroll
            for (int nf = 0; nf < 12; ++nf) accT[nf] = (f32x4){0.f, 0.f, 0.f, 0.f};
            #pragma unroll
            for (int kf = 0; kf < 6; ++kf) {
                bf16x8 a = (kf < 2)
                    ? *reinterpret_cast<const bf16x8*>(&dhcB[lr][kf * 32 + lk])
                    : *reinterpret_cast<const bf16x8*>(&dh1B[lr][(kf - 2) * 32 + lk]);
                #pragma unroll
                for (int nf = 0; nf < 12; ++nf) {
                    bf16x8 bg = *reinterpret_cast<const bf16x8*>(
                        Gram + (size_t)(nf * 16 + lr) * NW + kf * 32 + lk);
                    accT[nf] = __builtin_amdgcn_mfma_f32_16x16x32_bf16(a, bg, accT[nf], 0, 0, 0);
                }
            }
            #pragma unroll
            for (int nf = 0; nf < 12; ++nf)
                #pragma unroll
                for (int r = 0; r < 4; ++r)
                    Ts[lq * 4 + r][nf * 16 + lr] -= 0.01f * accT[nf][r];
            __syncthreads();
        }
    }
    // Dsbf = [sum dh1 | sum dhc] bf16
    #pragma unroll
    for (int nf = 0; nf < 8; ++nf)
        #pragma unroll
        for (int r = 0; r < 4; ++r)
            Dsbf[(size_t)(b16 + lq * 4 + r) * NW + nf * 16 + lr] = f2bf(ds1[nf][r]);
    #pragma unroll
    for (int nf = 0; nf < 4; ++nf)
        #pragma unroll
        for (int r = 0; r < 4; ++r)
            Dsbf[(size_t)(b16 + lq * 4 + r) * NW + 128 + nf * 16 + lr] = f2bf(ds2[nf][r]);
}

// ============ L5: pm = tanh(0.7e+0.3enc) - 0.01 * Dsum @ Wcat^T ============
__global__ __launch_bounds__(256) void final_k(const unsigned short* __restrict__ Dsbf,
        const unsigned short* __restrict__ Wcat, const float* __restrict__ tp,
        const float* __restrict__ cons, const float* __restrict__ e,
        float* __restrict__ pm) {
    __shared__ __align__(16) unsigned short As[64][72];
    __shared__ __align__(16) unsigned short Bs[256][72];
    const int bid = blockIdx.x, t = threadIdx.x;
    const int m0 = (bid >> 4) * 64;
    const int n0 = (bid & 15) * 256;
    const int w = t >> 6, l = t & 63;
    const int lr = l & 15, lk = (l >> 4) * 8;

    f32x4 acc[16];
    #pragma unroll
    for (int nf = 0; nf < 16; ++nf) acc[nf] = (f32x4){0.f, 0.f, 0.f, 0.f};

    for (int kt = 0; kt < NW; kt += 64) {
        #pragma unroll
        for (int c = 0; c < 2; ++c) {      // A: Dsbf 64x64
            int ch = t + c * 256;
            int row = ch >> 3, col8 = (ch & 7) * 8;
            *reinterpret_cast<float4*>(&As[row][col8]) =
                *reinterpret_cast<const float4*>(Dsbf + (size_t)(m0 + row) * NW + kt + col8);
        }
        #pragma unroll
        for (int c = 0; c < 8; ++c) {      // B: Wcat 256x64
            int ch = t + c * 256;
            int row = ch >> 3, col8 = (ch & 7) * 8;
            *reinterpret_cast<float4*>(&Bs[row][col8]) =
                *reinterpret_cast<const float4*>(Wcat + (size_t)(n0 + row) * NW + kt + col8);
        }
        __syncthreads();
        #pragma unroll
        for (int h = 0; h < 2; ++h) {
            bf16x8 a = *reinterpret_cast<const bf16x8*>(&As[w * 16 + lr][h * 32 + lk]);
            #pragma unroll
            for (int nf = 0; nf < 16; ++nf) {
                bf16x8 b = *reinterpret_cast<const bf16x8*>(&Bs[nf * 16 + lr][h * 32 + lk]);
                acc[nf] = __builtin_amdgcn_mfma_f32_16x16x32_bf16(a, b, acc[nf], 0, 0, 0);
            }
        }
        __syncthreads();
    }
    const int mrow = m0 + w * 16 + (l >> 4) * 4;
    #pragma unroll
    for (int nf = 0; nf < 16; ++nf) {
        int n = n0 + nf * 16 + lr;
        float ek = e[n];
        #pragma unroll
        for (int r = 0; r < 4; ++r) {
            int m = mrow + r;
            float encv = (n < PAR) ? tp[(size_t)m * PAR + n] : cons[m * CONS + (n - PAR)];
            pm[(size_t)m * PDIM + n] = fast_tanh(0.7f * ek + 0.3f * encv) - 0.01f * acc[nf][r];
        }
    }
}

extern "C" void kernel_launch(void* const* d_in, const int* in_sizes, int n_in,
                              void* d_out, int out_size, void* d_ws, size_t ws_size,
                              hipStream_t stream) {
    const float* tp   = (const float*)d_in[0];
    const float* cons = (const float*)d_in[1];
    // d_in[2] transverse_field, d_in[3] coupling: DEAD CODE (annealing is identity)
    const float* mp   = (const float*)d_in[4];
    const float* cw1  = (const float*)d_in[5];
    const float* cb1  = (const float*)d_in[6];
    const float* cw2  = (const float*)d_in[7];
    const float* cb2  = (const float*)d_in[8];
    const float* ow1  = (const float*)d_in[9];
    const float* ob1  = (const float*)d_in[10];
    const float* ow2  = (const float*)d_in[11];
    const float* ob2  = (const float*)d_in[12];
    const float* ow3  = (const float*)d_in[13];
    float* pm = (float*)d_out;

    float* f = (float*)d_ws;
    float* e      = f;  f += 4096;
    float* epart  = f;  f += 32 * 4096;
    float* Gpart  = f;  f += 8 * NW * NW;
    float* Tparts = f;  f += 8 * BATCH * NW;
    unsigned short* u = (unsigned short*)f;
    unsigned short* WT   = u;  u += NW * PDIM;
    unsigned short* Wcat = u;  u += PDIM * NW;
    unsigned short* Gram = u;  u += NW * NW;
    unsigned short* Dsbf = u;

    prep_all_k<<<3968, 256, 0, stream>>>(mp, cw1, ow1, epart, WT, Wcat);
    fin_gram_k<<<88, 256, 0, stream>>>(epart, WT, e, Gpart);
    gemmT_k<<<400, 256, 0, stream>>>(tp, cons, e, WT, Tparts, Gpart, Gram);
    refine_k<<<128, 64, 0, stream>>>(Tparts, cb1, cw2, cb2, ow1, ob1, ow2, ob2, ow3,
                                     Gram, Dsbf);
    final_k<<<512, 256, 0, stream>>>(Dsbf, Wcat, tp, cons, e, pm);
}

// Round 5
// 97.605 us; speedup vs baseline: 1.8887x; 1.4191x over previous
//
#include <hip/hip_runtime.h>
#include <math.h>

#define BATCH 2048
#define PDIM  4096
#define PAR   4086
#define CONS  10
#define NW    192     // 64 (cw1 cols) + 128 (ow1 cols)

typedef __attribute__((ext_vector_type(8))) short bf16x8;
typedef __attribute__((ext_vector_type(8))) unsigned short ushort8;
typedef __attribute__((ext_vector_type(4))) float f32x4;

__device__ __forceinline__ unsigned short f2bf(float f) {
    unsigned int u = __float_as_uint(f);
    u += 0x7FFFu + ((u >> 16) & 1u);      // RTNE
    return (unsigned short)(u >> 16);
}
__device__ __forceinline__ float bf2f(unsigned short u) {
    return __uint_as_float(((unsigned int)u) << 16);
}
__device__ __forceinline__ float fast_tanh(float z) {
    float a = fabsf(z);
    float ex = __expf(-2.f * a);                       // e^-2a
    float th = (1.f - ex) * __builtin_amdgcn_rcpf(1.f + ex);
    return copysignf(th, z);
}

// ============ L1: colmean_part + prep_WT + prep_Wcat (merged) ============
__global__ __launch_bounds__(256) void prep_all_k(const float* __restrict__ mp,
        const float* __restrict__ cw1, const float* __restrict__ ow1,
        float* __restrict__ epart, unsigned short* __restrict__ WT,
        unsigned short* __restrict__ Wcat) {
    __shared__ float tile[64][33];
    const int bid = blockIdx.x, t = threadIdx.x;
    if (bid < 512) {                       // colmean partial: 16 x 32
        int col = (bid & 15) * 256 + t;
        int z = bid >> 4;
        float s = 0.f;
        int r0 = z * 32;
        for (int r = 0; r < 32; ++r) s += mp[(size_t)(r0 + r) * PDIM + col];
        epart[(size_t)z * PDIM + col] = s;
    } else if (bid < 896) {                // prep_WT: 64 k-chunks x 6 j-chunks
        int g = bid - 512;
        int k0 = (g & 63) * 64, j0 = (g >> 6) * 32;
        const float* src; int lds_, jb;
        if (j0 < 64) { src = cw1; lds_ = 64;  jb = j0; }
        else         { src = ow1; lds_ = 128; jb = j0 - 64; }
        int jl = t & 31, kl0 = t >> 5;
        for (int kk = 0; kk < 64; kk += 8)
            tile[kk + kl0][jl] = src[(size_t)(k0 + kk + kl0) * lds_ + jb + jl];
        __syncthreads();
        int kl = t & 63, jl0 = t >> 6;
        for (int jj = 0; jj < 32; jj += 4)
            WT[(size_t)(j0 + jj + jl0) * PDIM + k0 + kl] = f2bf(tile[kl][jj + jl0]);
    } else {                               // prep_Wcat: 3072 blocks
        int idx = (bid - 896) * 256 + t;
        int n = idx / NW, j = idx - n * NW;
        float v = (j < 128) ? ow1[(size_t)n * 128 + j] : cw1[(size_t)n * 64 + (j - 128)];
        Wcat[idx] = f2bf(v);
    }
}

// ============ L2: colmean_fin + Gram split-K (merged) ============
__global__ __launch_bounds__(256) void fin_gram_k(const float* __restrict__ epart,
        const unsigned short* __restrict__ WT, float* __restrict__ e,
        float* __restrict__ Gpart) {
    __shared__ __align__(16) unsigned short As[64][72];
    __shared__ __align__(16) unsigned short Bs[64][72];
    const int bid = blockIdx.x, t = threadIdx.x;
    if (bid < 16) {                        // colmean finalize
        int col = bid * 256 + t;
        float s = 0.f;
        #pragma unroll
        for (int z = 0; z < 32; ++z) s += epart[(size_t)z * PDIM + col];
        e[col] = s * (1.0f / 1024.0f);
        return;
    }
    int g = bid - 16;                      // 72 blocks: Gram = WT @ WT^T (split-K 8)
    const int kz = g & 7; g >>= 3;
    const int m0 = (g % 3) * 64, n0 = (g / 3) * 64;
    const int w = t >> 6, l = t & 63;
    const int lr = l & 15, lk = (l >> 4) * 8;
    f32x4 acc[4];
    #pragma unroll
    for (int nf = 0; nf < 4; ++nf) acc[nf] = (f32x4){0.f, 0.f, 0.f, 0.f};
    for (int kt = 0; kt < 512; kt += 64) {
        const int kbase = kz * 512 + kt;
        #pragma unroll
        for (int c = 0; c < 2; ++c) {
            int ch = t + c * 256;
            int row = ch >> 3, col8 = (ch & 7) * 8;
            *reinterpret_cast<float4*>(&As[row][col8]) =
                *reinterpret_cast<const float4*>(WT + (size_t)(m0 + row) * PDIM + kbase + col8);
            *reinterpret_cast<float4*>(&Bs[row][col8]) =
                *reinterpret_cast<const float4*>(WT + (size_t)(n0 + row) * PDIM + kbase + col8);
        }
        __syncthreads();
        #pragma unroll
        for (int h = 0; h < 2; ++h) {
            bf16x8 a = *reinterpret_cast<const bf16x8*>(&As[w * 16 + lr][h * 32 + lk]);
            #pragma unroll
            for (int nf = 0; nf < 4; ++nf) {
                bf16x8 b = *reinterpret_cast<const bf16x8*>(&Bs[nf * 16 + lr][h * 32 + lk]);
                acc[nf] = __builtin_amdgcn_mfma_f32_16x16x32_bf16(a, b, acc[nf], 0, 0, 0);
            }
        }
        __syncthreads();
    }
    float* op = Gpart + (size_t)kz * NW * NW + (size_t)(m0 + w * 16 + (l >> 4) * 4) * NW + n0;
    #pragma unroll
    for (int nf = 0; nf < 4; ++nf)
        #pragma unroll
        for (int r = 0; r < 4; ++r)
            op[(size_t)r * NW + nf * 16 + lr] = acc[nf][r];
}

// ============ L3: T = tanh(0.7e+0.3enc) @ Wf  (N=192 per block, split-K 8) ============
//             + 144 extra blocks reduce Gpart -> Gram (bf16)
__global__ __launch_bounds__(256) void gemmT_k(const float* __restrict__ tp,
        const float* __restrict__ cons, const float* __restrict__ e,
        const unsigned short* __restrict__ WT, float* __restrict__ parts,
        const float* __restrict__ Gpart, unsigned short* __restrict__ Gram) {
    __shared__ __align__(16) unsigned short As[64][72];
    __shared__ __align__(16) unsigned short Bs[NW][72];
    const int bid = blockIdx.x, t = threadIdx.x;
    if (bid >= 256) {                      // Gram reduce
        int idx = (bid - 256) * 256 + t;   // 144*256 = 36864
        float s = 0.f;
        #pragma unroll
        for (int z = 0; z < 8; ++z) s += Gpart[(size_t)z * NW * NW + idx];
        Gram[idx] = f2bf(s);
        return;
    }
    const int m0 = (bid >> 3) * 64;
    const int kz = bid & 7;
    const int w = t >> 6, l = t & 63;
    const int lr = l & 15, lk = (l >> 4) * 8;

    f32x4 acc[12];
    #pragma unroll
    for (int nf = 0; nf < 12; ++nf) acc[nf] = (f32x4){0.f, 0.f, 0.f, 0.f};

    const int colA = t & 63, rowA0 = t >> 6;
    for (int kt = 0; kt < 512; kt += 64) {
        const int kbase = kz * 512 + kt;
        // A staging: params0 computed on the fly (tanh), never materialized
        const int k = kbase + colA;
        const float ek = e[k];
        #pragma unroll
        for (int c = 0; c < 16; ++c) {
            int row = rowA0 + c * 4;
            int m = m0 + row;
            float encv = (k < PAR) ? tp[(size_t)m * PAR + k] : cons[m * CONS + (k - PAR)];
            As[row][colA] = f2bf(fast_tanh(0.7f * ek + 0.3f * encv));
        }
        #pragma unroll
        for (int c = 0; c < 6; ++c) {      // B staging: 192x64 bf16
            int ch = t + c * 256;
            int row = ch >> 3, col8 = (ch & 7) * 8;
            *reinterpret_cast<float4*>(&Bs[row][col8]) =
                *reinterpret_cast<const float4*>(WT + (size_t)row * PDIM + kbase + col8);
        }
        __syncthreads();
        #pragma unroll
        for (int h = 0; h < 2; ++h) {
            bf16x8 a = *reinterpret_cast<const bf16x8*>(&As[w * 16 + lr][h * 32 + lk]);
            #pragma unroll
            for (int nf = 0; nf < 12; ++nf) {
                bf16x8 b = *reinterpret_cast<const bf16x8*>(&Bs[nf * 16 + lr][h * 32 + lk]);
                acc[nf] = __builtin_amdgcn_mfma_f32_16x16x32_bf16(a, b, acc[nf], 0, 0, 0);
            }
        }
        __syncthreads();
    }
    float* op = parts + (size_t)kz * BATCH * NW + (size_t)(m0 + w * 16 + (l >> 4) * 4) * NW;
    #pragma unroll
    for (int nf = 0; nf < 12; ++nf)
        #pragma unroll
        for (int r = 0; r < 4; ++r)
            op[(size_t)r * NW + nf * 16 + lr] = acc[nf][r];
}

// ============ L4: fused 3-step refinement — MFMA, 4 waves / 16 batch rows ============
// Waves split each stage's N-fragments; stages 2/6 (N=10) on wave 0 only.
//  hc=relu(T[:,:64]+cb1) -> cv=sigm(hc@cw2) -> h1=relu(T[:,64:]+ob1+cv@ow1c)
//  -> dh2=(h1@ow2+ob2>0)?ow3:0 -> dh1=(h1>0)*(dh2@ow2^T) -> dz2=(dh1@ow1c^T)*cv'
//  -> dhc=(hc>0)*(dz2@cw2^T) -> T -= 0.01*[dhc|dh1]@Gram (Gram from L2)
__global__ __launch_bounds__(256) void refine_k(const float* __restrict__ Tparts,
        const float* __restrict__ cb1, const float* __restrict__ cw2,
        const float* __restrict__ cb2, const float* __restrict__ ow1,
        const float* __restrict__ ob1, const float* __restrict__ ow2,
        const float* __restrict__ ob2, const float* __restrict__ ow3,
        const unsigned short* __restrict__ Gram, unsigned short* __restrict__ Dsbf) {
    __shared__ __align__(16) float Ts[16][196];
    __shared__ __align__(16) unsigned short hcB[16][72];
    __shared__ __align__(16) unsigned short h1B[16][136];
    __shared__ __align__(16) unsigned short dh2B[16][72];
    __shared__ __align__(16) unsigned short dh1B[16][136];
    __shared__ __align__(16) unsigned short dhcB[16][72];
    __shared__ __align__(16) unsigned short cvA[16][40];
    __shared__ __align__(16) unsigned short dz2A[16][40];
    __shared__ __align__(16) unsigned short cw2B[16][72];    // B[n][k]=cw2[k][n], n<10
    __shared__ __align__(16) unsigned short ow1cB[128][40];  // B[n][k]=ow1[4096+k][n], k<10
    __shared__ __align__(16) unsigned short ow2B[64][136];   // B[n][k]=ow2[k][n]
    __shared__ __align__(16) unsigned short ow2TB[128][72];  // B[n][k]=ow2[n][k]
    __shared__ __align__(16) unsigned short ow1cTB[16][136]; // B[n][k]=ow1[4096+n][k], n<10
    __shared__ __align__(16) unsigned short cw2TB[64][40];   // B[n][k]=cw2[n][k], k<10
    __shared__ float cb1f[64], ob1f[128], ob2f[64], cb2f[16], ow3f[64];

    const int t = threadIdx.x;            // 0..255
    const int w = t >> 6, l = t & 63;
    const int b16 = blockIdx.x * 16;
    const int lr = l & 15, lq = l >> 4, lk = lq * 8;

    // ---- biases (coalesced, one pass) ----
    if (t < 64)       { cb1f[t] = cb1[t]; ob2f[t] = ob2[t]; ow3f[t] = ow3[t]; }
    else if (t < 192) { ob1f[t - 64] = ob1[t - 64]; }
    else if (t < 208) { int i = t - 192; cb2f[i] = (i < 10) ? cb2[i] : 0.f; }
    // ---- zero-init padded tiles ----
    for (int i = t; i < 16 * 72;  i += 256) (&cw2B[0][0])[i] = 0;
    for (int i = t; i < 128 * 40; i += 256) (&ow1cB[0][0])[i] = 0;
    for (int i = t; i < 16 * 136; i += 256) (&ow1cTB[0][0])[i] = 0;
    for (int i = t; i < 64 * 40;  i += 256) (&cw2TB[0][0])[i] = 0;
    for (int i = t; i < 16 * 40;  i += 256) { (&cvA[0][0])[i] = 0; (&dz2A[0][0])[i] = 0; }
    __syncthreads();
    // ---- weight tiles (block-wide strided, coalesced reads) ----
    for (int i = t; i < 640; i += 256)  { int k = i / 10, n = i - k * 10;       // cw2 flat
        cw2B[n][k] = f2bf(cw2[i]); }
    for (int i = t; i < 640; i += 256)  { int n = i / 10, k = i - n * 10;
        cw2TB[n][k] = f2bf(cw2[i]); }
    for (int i = t; i < 1280; i += 256) { int k = i >> 7, n = i & 127;          // ow1c flat
        ow1cB[n][k] = f2bf(ow1[(size_t)(4096 + k) * 128 + n]); }
    for (int i = t; i < 8192; i += 256) { int k = i >> 6, n = i & 63;           // ow2 flat
        ow2B[n][k] = f2bf(ow2[i]); }
    for (int i = t; i < 2048; i += 256) { int n = i >> 4, c4 = (i & 15) * 4;    // ow2 rows
        float4 v = *reinterpret_cast<const float4*>(ow2 + n * 64 + c4);
        unsigned int p0 = (unsigned int)f2bf(v.x) | ((unsigned int)f2bf(v.y) << 16);
        unsigned int p1 = (unsigned int)f2bf(v.z) | ((unsigned int)f2bf(v.w) << 16);
        *reinterpret_cast<uint2*>(&ow2TB[n][c4]) = make_uint2(p0, p1); }
    for (int i = t; i < 320; i += 256)  { int n = i >> 5, c4 = (i & 31) * 4;    // ow1c rows
        float4 v = *reinterpret_cast<const float4*>(ow1 + (size_t)(4096 + n) * 128 + c4);
        unsigned int p0 = (unsigned int)f2bf(v.x) | ((unsigned int)f2bf(v.y) << 16);
        unsigned int p1 = (unsigned int)f2bf(v.z) | ((unsigned int)f2bf(v.w) << 16);
        *reinterpret_cast<uint2*>(&ow1cTB[n][c4]) = make_uint2(p0, p1); }
    // ---- Ts = sum_z Tparts[z][rows][:] (256 threads, 3 float4-groups each) ----
    for (int i = t; i < 768; i += 256) {
        int row = i / 48, c4 = (i - row * 48) * 4;
        const float* src = Tparts + (size_t)(b16 + row) * NW + c4;
        float4 s = make_float4(0.f, 0.f, 0.f, 0.f);
        #pragma unroll
        for (int z = 0; z < 8; ++z) {
            float4 v = *reinterpret_cast<const float4*>(src + (size_t)z * BATCH * NW);
            s.x += v.x; s.y += v.y; s.z += v.z; s.w += v.w;
        }
        *reinterpret_cast<float4*>(&Ts[row][c4]) = s;
    }
    __syncthreads();

    f32x4 ds1[2], ds2;                    // per-wave dsum slices
    ds1[0] = (f32x4){0.f, 0.f, 0.f, 0.f};
    ds1[1] = (f32x4){0.f, 0.f, 0.f, 0.f};
    ds2    = (f32x4){0.f, 0.f, 0.f, 0.f};
    float sv[4];                          // sigmoid' — wave 0 registers only

    for (int step = 0; step < 3; ++step) {
        // (1) hc = relu(T[:, :64] + cb1)   [elementwise, all 256 threads]
        for (int i = t; i < 1024; i += 256) { int row = i >> 6, k = i & 63;
            hcB[row][k] = f2bf(fmaxf(Ts[row][k] + cb1f[k], 0.f)); }
        __syncthreads();
        // (2) cv = sigmoid(hc @ cw2)       [wave 0]
        if (w == 0) {
            f32x4 accv = (f32x4){0.f, 0.f, 0.f, 0.f};
            #pragma unroll
            for (int h = 0; h < 2; ++h) {
                bf16x8 a = *reinterpret_cast<const bf16x8*>(&hcB[lr][h * 32 + lk]);
                bf16x8 bb = *reinterpret_cast<const bf16x8*>(&cw2B[lr][h * 32 + lk]);
                accv = __builtin_amdgcn_mfma_f32_16x16x32_bf16(a, bb, accv, 0, 0, 0);
            }
            #pragma unroll
            for (int r = 0; r < 4; ++r) {
                float c = 1.f / (1.f + __expf(-(accv[r] + cb2f[lr])));
                sv[r] = c * (1.f - c);
                cvA[lq * 4 + r][lr] = f2bf(c);
            }
        }
        __syncthreads();
        // (3) h1 = relu(T[:,64:] + ob1 + cv @ ow1c)   [2 nf per wave]
        {
            bf16x8 a = *reinterpret_cast<const bf16x8*>(&cvA[lr][lk]);
            #pragma unroll
            for (int j = 0; j < 2; ++j) {
                int nf = w * 2 + j;
                bf16x8 bb = *reinterpret_cast<const bf16x8*>(&ow1cB[nf * 16 + lr][lk]);
                f32x4 acch = __builtin_amdgcn_mfma_f32_16x16x32_bf16(a, bb,
                            (f32x4){0.f, 0.f, 0.f, 0.f}, 0, 0, 0);
                #pragma unroll
                for (int r = 0; r < 4; ++r) {
                    int row = lq * 4 + r, col = nf * 16 + lr;
                    float v = acch[r] + Ts[row][64 + col] + ob1f[col];
                    h1B[row][col] = f2bf(fmaxf(v, 0.f));
                }
            }
        }
        __syncthreads();
        // (4) dh2 = (h1@ow2+ob2 > 0) ? ow3 : 0   [1 nf per wave]
        {
            f32x4 accz = (f32x4){0.f, 0.f, 0.f, 0.f};
            #pragma unroll
            for (int kc = 0; kc < 4; ++kc) {
                bf16x8 a = *reinterpret_cast<const bf16x8*>(&h1B[lr][kc * 32 + lk]);
                bf16x8 bb = *reinterpret_cast<const bf16x8*>(&ow2B[w * 16 + lr][kc * 32 + lk]);
                accz = __builtin_amdgcn_mfma_f32_16x16x32_bf16(a, bb, accz, 0, 0, 0);
            }
            #pragma unroll
            for (int r = 0; r < 4; ++r) {
                int col = w * 16 + lr;
                float z = accz[r] + ob2f[col];
                dh2B[lq * 4 + r][col] = f2bf((z > 0.f) ? ow3f[col] : 0.f);
            }
        }
        __syncthreads();
        // (5) dh1 = (h1>0) * (dh2 @ ow2^T)   [2 nf per wave]
        #pragma unroll
        for (int j = 0; j < 2; ++j) {
            int nf = w * 2 + j;
            f32x4 accd = (f32x4){0.f, 0.f, 0.f, 0.f};
            #pragma unroll
            for (int kc = 0; kc < 2; ++kc) {
                bf16x8 a = *reinterpret_cast<const bf16x8*>(&dh2B[lr][kc * 32 + lk]);
                bf16x8 bb = *reinterpret_cast<const bf16x8*>(&ow2TB[nf * 16 + lr][kc * 32 + lk]);
                accd = __builtin_amdgcn_mfma_f32_16x16x32_bf16(a, bb, accd, 0, 0, 0);
            }
            #pragma unroll
            for (int r = 0; r < 4; ++r) {
                int row = lq * 4 + r, col = nf * 16 + lr;
                float v = (bf2f(h1B[row][col]) > 0.f) ? accd[r] : 0.f;
                ds1[j][r] += v;
                dh1B[row][col] = f2bf(v);
            }
        }
        __syncthreads();
        // (6) dz2 = (dh1 @ ow1c^T) * cv*(1-cv)   [wave 0]
        if (w == 0) {
            f32x4 accq = (f32x4){0.f, 0.f, 0.f, 0.f};
            #pragma unroll
            for (int kc = 0; kc < 4; ++kc) {
                bf16x8 a = *reinterpret_cast<const bf16x8*>(&dh1B[lr][kc * 32 + lk]);
                bf16x8 bb = *reinterpret_cast<const bf16x8*>(&ow1cTB[lr][kc * 32 + lk]);
                accq = __builtin_amdgcn_mfma_f32_16x16x32_bf16(a, bb, accq, 0, 0, 0);
            }
            #pragma unroll
            for (int r = 0; r < 4; ++r)
                dz2A[lq * 4 + r][lr] = f2bf(accq[r] * sv[r]);
        }
        __syncthreads();
        // (7) dhc = (hc>0) * (dz2 @ cw2^T)   [1 nf per wave]
        {
            bf16x8 a = *reinterpret_cast<const bf16x8*>(&dz2A[lr][lk]);
            bf16x8 bb = *reinterpret_cast<const bf16x8*>(&cw2TB[w * 16 + lr][lk]);
            f32x4 accc = __builtin_amdgcn_mfma_f32_16x16x32_bf16(a, bb,
                        (f32x4){0.f, 0.f, 0.f, 0.f}, 0, 0, 0);
            #pragma unroll
            for (int r = 0; r < 4; ++r) {
                int row = lq * 4 + r, col = w * 16 + lr;
                float v = (bf2f(hcB[row][col]) > 0.f) ? accc[r] : 0.f;
                ds2[r] += v;
                dhcB[row][col] = f2bf(v);
            }
        }
        __syncthreads();
        // (8) T -= 0.01 * [dhc | dh1] @ Gram   [3 nf per wave, Gram from L2]
        if (step < 2) {
            f32x4 accT[3];
            #pragma unroll
            for (int j = 0; j < 3; ++j) accT[j] = (f32x4){0.f, 0.f, 0.f, 0.f};
            #pragma unroll
            for (int kf = 0; kf < 6; ++kf) {
                bf16x8 a = (kf < 2)
                    ? *reinterpret_cast<const bf16x8*>(&dhcB[lr][kf * 32 + lk])
                    : *reinterpret_cast<const bf16x8*>(&dh1B[lr][(kf - 2) * 32 + lk]);
                #pragma unroll
                for (int j = 0; j < 3; ++j) {
                    int nf = w * 3 + j;
                    bf16x8 bg = *reinterpret_cast<const bf16x8*>(
                        Gram + (size_t)(nf * 16 + lr) * NW + kf * 32 + lk);
                    accT[j] = __builtin_amdgcn_mfma_f32_16x16x32_bf16(a, bg, accT[j], 0, 0, 0);
                }
            }
            #pragma unroll
            for (int j = 0; j < 3; ++j)
                #pragma unroll
                for (int r = 0; r < 4; ++r)
                    Ts[lq * 4 + r][(w * 3 + j) * 16 + lr] -= 0.01f * accT[j][r];
            __syncthreads();
        }
    }
    // Dsbf = [sum dh1 | sum dhc] bf16 — each wave writes its N-slices
    #pragma unroll
    for (int j = 0; j < 2; ++j)
        #pragma unroll
        for (int r = 0; r < 4; ++r)
            Dsbf[(size_t)(b16 + lq * 4 + r) * NW + (w * 2 + j) * 16 + lr] = f2bf(ds1[j][r]);
    #pragma unroll
    for (int r = 0; r < 4; ++r)
        Dsbf[(size_t)(b16 + lq * 4 + r) * NW + 128 + w * 16 + lr] = f2bf(ds2[r]);
}

// ============ L5: pm = tanh(0.7e+0.3enc) - 0.01 * Dsum @ Wcat^T ============
__global__ __launch_bounds__(256) void final_k(const unsigned short* __restrict__ Dsbf,
        const unsigned short* __restrict__ Wcat, const float* __restrict__ tp,
        const float* __restrict__ cons, const float* __restrict__ e,
        float* __restrict__ pm) {
    __shared__ __align__(16) unsigned short As[64][72];
    __shared__ __align__(16) unsigned short Bs[256][72];
    const int bid = blockIdx.x, t = threadIdx.x;
    const int m0 = (bid >> 4) * 64;
    const int n0 = (bid & 15) * 256;
    const int w = t >> 6, l = t & 63;
    const int lr = l & 15, lk = (l >> 4) * 8;

    f32x4 acc[16];
    #pragma unroll
    for (int nf = 0; nf < 16; ++nf) acc[nf] = (f32x4){0.f, 0.f, 0.f, 0.f};

    for (int kt = 0; kt < NW; kt += 64) {
        #pragma unroll
        for (int c = 0; c < 2; ++c) {      // A: Dsbf 64x64
            int ch = t + c * 256;
            int row = ch >> 3, col8 = (ch & 7) * 8;
            *reinterpret_cast<float4*>(&As[row][col8]) =
                *reinterpret_cast<const float4*>(Dsbf + (size_t)(m0 + row) * NW + kt + col8);
        }
        #pragma unroll
        for (int c = 0; c < 8; ++c) {      // B: Wcat 256x64
            int ch = t + c * 256;
            int row = ch >> 3, col8 = (ch & 7) * 8;
            *reinterpret_cast<float4*>(&Bs[row][col8]) =
                *reinterpret_cast<const float4*>(Wcat + (size_t)(n0 + row) * NW + kt + col8);
        }
        __syncthreads();
        #pragma unroll
        for (int h = 0; h < 2; ++h) {
            bf16x8 a = *reinterpret_cast<const bf16x8*>(&As[w * 16 + lr][h * 32 + lk]);
            #pragma unroll
            for (int nf = 0; nf < 16; ++nf) {
                bf16x8 b = *reinterpret_cast<const bf16x8*>(&Bs[nf * 16 + lr][h * 32 + lk]);
                acc[nf] = __builtin_amdgcn_mfma_f32_16x16x32_bf16(a, b, acc[nf], 0, 0, 0);
            }
        }
        __syncthreads();
    }
    const int mrow = m0 + w * 16 + (l >> 4) * 4;
    #pragma unroll
    for (int nf = 0; nf < 16; ++nf) {
        int n = n0 + nf * 16 + lr;
        float ek = e[n];
        #pragma unroll
        for (int r = 0; r < 4; ++r) {
            int m = mrow + r;
            float encv = (n < PAR) ? tp[(size_t)m * PAR + n] : cons[m * CONS + (n - PAR)];
            pm[(size_t)m * PDIM + n] = fast_tanh(0.7f * ek + 0.3f * encv) - 0.01f * acc[nf][r];
        }
    }
}

extern "C" void kernel_launch(void* const* d_in, const int* in_sizes, int n_in,
                              void* d_out, int out_size, void* d_ws, size_t ws_size,
                              hipStream_t stream) {
    const float* tp   = (const float*)d_in[0];
    const float* cons = (const float*)d_in[1];
    // d_in[2] transverse_field, d_in[3] coupling: DEAD CODE (annealing is identity)
    const float* mp   = (const float*)d_in[4];
    const float* cw1  = (const float*)d_in[5];
    const float* cb1  = (const float*)d_in[6];
    const float* cw2  = (const float*)d_in[7];
    const float* cb2  = (const float*)d_in[8];
    const float* ow1  = (const float*)d_in[9];
    const float* ob1  = (const float*)d_in[10];
    const float* ow2  = (const float*)d_in[11];
    const float* ob2  = (const float*)d_in[12];
    const float* ow3  = (const float*)d_in[13];
    float* pm = (float*)d_out;

    float* f = (float*)d_ws;
    float* e      = f;  f += 4096;
    float* epart  = f;  f += 32 * 4096;
    float* Gpart  = f;  f += 8 * NW * NW;
    float* Tparts = f;  f += 8 * BATCH * NW;
    unsigned short* u = (unsigned short*)f;
    unsigned short* WT   = u;  u += NW * PDIM;
    unsigned short* Wcat = u;  u += PDIM * NW;
    unsigned short* Gram = u;  u += NW * NW;
    unsigned short* Dsbf = u;

    prep_all_k<<<3968, 256, 0, stream>>>(mp, cw1, ow1, epart, WT, Wcat);
    fin_gram_k<<<88, 256, 0, stream>>>(epart, WT, e, Gpart);
    gemmT_k<<<400, 256, 0, stream>>>(tp, cons, e, WT, Tparts, Gpart, Gram);
    refine_k<<<128, 256, 0, stream>>>(Tparts, cb1, cw2, cb2, ow1, ob1, ow2, ob2, ow3,
                                      Gram, Dsbf);
    final_k<<<512, 256, 0, stream>>>(Dsbf, Wcat, tp, cons, e, pm);
}

// Round 6
// 86.611 us; speedup vs baseline: 2.1285x; 1.1269x over previous
//
#include <hip/hip_runtime.h>
#include <math.h>

#define BATCH 2048
#define PDIM  4096
#define PAR   4086
#define CONS  10
#define NW    192     // 64 (cw1 cols) + 128 (ow1 cols)

typedef __attribute__((ext_vector_type(8))) short bf16x8;
typedef __attribute__((ext_vector_type(8))) unsigned short ushort8;
typedef __attribute__((ext_vector_type(4))) float f32x4;

__device__ __forceinline__ unsigned short f2bf(float f) {
    unsigned int u = __float_as_uint(f);
    u += 0x7FFFu + ((u >> 16) & 1u);      // RTNE
    return (unsigned short)(u >> 16);
}
__device__ __forceinline__ float bf2f(unsigned short u) {
    return __uint_as_float(((unsigned int)u) << 16);
}
__device__ __forceinline__ float fast_tanh(float z) {
    float a = fabsf(z);
    float ex = __expf(-2.f * a);                       // e^-2a
    float th = (1.f - ex) * __builtin_amdgcn_rcpf(1.f + ex);
    return copysignf(th, z);
}

// ============ L1: colmean_part + prep_WT + prep_Wcat (merged) ============
__global__ __launch_bounds__(256) void prep_all_k(const float* __restrict__ mp,
        const float* __restrict__ cw1, const float* __restrict__ ow1,
        float* __restrict__ epart, unsigned short* __restrict__ WT,
        unsigned short* __restrict__ Wcat) {
    __shared__ float tile[64][33];
    const int bid = blockIdx.x, t = threadIdx.x;
    if (bid < 512) {                       // colmean partial: 16 x 32
        int col = (bid & 15) * 256 + t;
        int z = bid >> 4;
        float s = 0.f;
        int r0 = z * 32;
        for (int r = 0; r < 32; ++r) s += mp[(size_t)(r0 + r) * PDIM + col];
        epart[(size_t)z * PDIM + col] = s;
    } else if (bid < 896) {                // prep_WT: 64 k-chunks x 6 j-chunks
        int g = bid - 512;
        int k0 = (g & 63) * 64, j0 = (g >> 6) * 32;
        const float* src; int lds_, jb;
        if (j0 < 64) { src = cw1; lds_ = 64;  jb = j0; }
        else         { src = ow1; lds_ = 128; jb = j0 - 64; }
        int jl = t & 31, kl0 = t >> 5;
        for (int kk = 0; kk < 64; kk += 8)
            tile[kk + kl0][jl] = src[(size_t)(k0 + kk + kl0) * lds_ + jb + jl];
        __syncthreads();
        int kl = t & 63, jl0 = t >> 6;
        for (int jj = 0; jj < 32; jj += 4)
            WT[(size_t)(j0 + jj + jl0) * PDIM + k0 + kl] = f2bf(tile[kl][jj + jl0]);
    } else {                               // prep_Wcat: 3072 blocks
        int idx = (bid - 896) * 256 + t;
        int n = idx / NW, j = idx - n * NW;
        float v = (j < 128) ? ow1[(size_t)n * 128 + j] : cw1[(size_t)n * 64 + (j - 128)];
        Wcat[idx] = f2bf(v);
    }
}

// ============ L2: colmean_fin + Gram split-K (merged) ============
__global__ __launch_bounds__(256) void fin_gram_k(const float* __restrict__ epart,
        const unsigned short* __restrict__ WT, float* __restrict__ e,
        float* __restrict__ Gpart) {
    __shared__ __align__(16) unsigned short As[64][72];
    __shared__ __align__(16) unsigned short Bs[64][72];
    const int bid = blockIdx.x, t = threadIdx.x;
    if (bid < 16) {                        // colmean finalize
        int col = bid * 256 + t;
        float s = 0.f;
        #pragma unroll
        for (int z = 0; z < 32; ++z) s += epart[(size_t)z * PDIM + col];
        e[col] = s * (1.0f / 1024.0f);
        return;
    }
    int g = bid - 16;                      // 72 blocks: Gram = WT @ WT^T (split-K 8)
    const int kz = g & 7; g >>= 3;
    const int m0 = (g % 3) * 64, n0 = (g / 3) * 64;
    const int w = t >> 6, l = t & 63;
    const int lr = l & 15, lk = (l >> 4) * 8;
    f32x4 acc[4];
    #pragma unroll
    for (int nf = 0; nf < 4; ++nf) acc[nf] = (f32x4){0.f, 0.f, 0.f, 0.f};
    for (int kt = 0; kt < 512; kt += 64) {
        const int kbase = kz * 512 + kt;
        #pragma unroll
        for (int c = 0; c < 2; ++c) {
            int ch = t + c * 256;
            int row = ch >> 3, col8 = (ch & 7) * 8;
            *reinterpret_cast<float4*>(&As[row][col8]) =
                *reinterpret_cast<const float4*>(WT + (size_t)(m0 + row) * PDIM + kbase + col8);
            *reinterpret_cast<float4*>(&Bs[row][col8]) =
                *reinterpret_cast<const float4*>(WT + (size_t)(n0 + row) * PDIM + kbase + col8);
        }
        __syncthreads();
        #pragma unroll
        for (int h = 0; h < 2; ++h) {
            bf16x8 a = *reinterpret_cast<const bf16x8*>(&As[w * 16 + lr][h * 32 + lk]);
            #pragma unroll
            for (int nf = 0; nf < 4; ++nf) {
                bf16x8 b = *reinterpret_cast<const bf16x8*>(&Bs[nf * 16 + lr][h * 32 + lk]);
                acc[nf] = __builtin_amdgcn_mfma_f32_16x16x32_bf16(a, b, acc[nf], 0, 0, 0);
            }
        }
        __syncthreads();
    }
    float* op = Gpart + (size_t)kz * NW * NW + (size_t)(m0 + w * 16 + (l >> 4) * 4) * NW + n0;
    #pragma unroll
    for (int nf = 0; nf < 4; ++nf)
        #pragma unroll
        for (int r = 0; r < 4; ++r)
            op[(size_t)r * NW + nf * 16 + lr] = acc[nf][r];
}

// ============ L3: T = tanh(0.7e+0.3enc) @ Wf  (N=192 per block, split-K 8) ============
//             + 144 extra blocks reduce Gpart -> Gram (bf16)
__global__ __launch_bounds__(256) void gemmT_k(const float* __restrict__ tp,
        const float* __restrict__ cons, const float* __restrict__ e,
        const unsigned short* __restrict__ WT, float* __restrict__ parts,
        const float* __restrict__ Gpart, unsigned short* __restrict__ Gram) {
    __shared__ __align__(16) unsigned short As[64][72];
    __shared__ __align__(16) unsigned short Bs[NW][72];
    const int bid = blockIdx.x, t = threadIdx.x;
    if (bid >= 256) {                      // Gram reduce
        int idx = (bid - 256) * 256 + t;   // 144*256 = 36864
        float s = 0.f;
        #pragma unroll
        for (int z = 0; z < 8; ++z) s += Gpart[(size_t)z * NW * NW + idx];
        Gram[idx] = f2bf(s);
        return;
    }
    const int m0 = (bid >> 3) * 64;
    const int kz = bid & 7;
    const int w = t >> 6, l = t & 63;
    const int lr = l & 15, lk = (l >> 4) * 8;

    f32x4 acc[12];
    #pragma unroll
    for (int nf = 0; nf < 12; ++nf) acc[nf] = (f32x4){0.f, 0.f, 0.f, 0.f};

    const int colA = t & 63, rowA0 = t >> 6;
    for (int kt = 0; kt < 512; kt += 64) {
        const int kbase = kz * 512 + kt;
        // A staging: params0 computed on the fly (tanh), never materialized
        const int k = kbase + colA;
        const float ek = e[k];
        #pragma unroll
        for (int c = 0; c < 16; ++c) {
            int row = rowA0 + c * 4;
            int m = m0 + row;
            float encv = (k < PAR) ? tp[(size_t)m * PAR + k] : cons[m * CONS + (k - PAR)];
            As[row][colA] = f2bf(fast_tanh(0.7f * ek + 0.3f * encv));
        }
        #pragma unroll
        for (int c = 0; c < 6; ++c) {      // B staging: 192x64 bf16
            int ch = t + c * 256;
            int row = ch >> 3, col8 = (ch & 7) * 8;
            *reinterpret_cast<float4*>(&Bs[row][col8]) =
                *reinterpret_cast<const float4*>(WT + (size_t)row * PDIM + kbase + col8);
        }
        __syncthreads();
        #pragma unroll
        for (int h = 0; h < 2; ++h) {
            bf16x8 a = *reinterpret_cast<const bf16x8*>(&As[w * 16 + lr][h * 32 + lk]);
            #pragma unroll
            for (int nf = 0; nf < 12; ++nf) {
                bf16x8 b = *reinterpret_cast<const bf16x8*>(&Bs[nf * 16 + lr][h * 32 + lk]);
                acc[nf] = __builtin_amdgcn_mfma_f32_16x16x32_bf16(a, b, acc[nf], 0, 0, 0);
            }
        }
        __syncthreads();
    }
    float* op = parts + (size_t)kz * BATCH * NW + (size_t)(m0 + w * 16 + (l >> 4) * 4) * NW;
    #pragma unroll
    for (int nf = 0; nf < 12; ++nf)
        #pragma unroll
        for (int r = 0; r < 4; ++r)
            op[(size_t)r * NW + nf * 16 + lr] = acc[nf][r];
}

// ============ L4: fused 3-step refinement — MFMA, 4 waves / 16 batch rows ============
__global__ __launch_bounds__(256) void refine_k(const float* __restrict__ Tparts,
        const float* __restrict__ cb1, const float* __restrict__ cw2,
        const float* __restrict__ cb2, const float* __restrict__ ow1,
        const float* __restrict__ ob1, const float* __restrict__ ow2,
        const float* __restrict__ ob2, const float* __restrict__ ow3,
        const unsigned short* __restrict__ Gram, unsigned short* __restrict__ Dsbf) {
    __shared__ __align__(16) float Ts[16][196];
    __shared__ __align__(16) unsigned short hcB[16][72];
    __shared__ __align__(16) unsigned short h1B[16][136];
    __shared__ __align__(16) unsigned short dh2B[16][72];
    __shared__ __align__(16) unsigned short dh1B[16][136];
    __shared__ __align__(16) unsigned short dhcB[16][72];
    __shared__ __align__(16) unsigned short cvA[16][40];
    __shared__ __align__(16) unsigned short dz2A[16][40];
    __shared__ __align__(16) unsigned short cw2B[16][72];    // B[n][k]=cw2[k][n], n<10
    __shared__ __align__(16) unsigned short ow1cB[128][40];  // B[n][k]=ow1[4096+k][n], k<10
    __shared__ __align__(16) unsigned short ow2B[64][136];   // B[n][k]=ow2[k][n]
    __shared__ __align__(16) unsigned short ow2TB[128][72];  // B[n][k]=ow2[n][k]
    __shared__ __align__(16) unsigned short ow1cTB[16][136]; // B[n][k]=ow1[4096+n][k], n<10
    __shared__ __align__(16) unsigned short cw2TB[64][40];   // B[n][k]=cw2[n][k], k<10
    __shared__ float cb1f[64], ob1f[128], ob2f[64], cb2f[16], ow3f[64];

    const int t = threadIdx.x;            // 0..255
    const int w = t >> 6, l = t & 63;
    const int b16 = blockIdx.x * 16;
    const int lr = l & 15, lq = l >> 4, lk = lq * 8;

    // ---- biases (coalesced, one pass) ----
    if (t < 64)       { cb1f[t] = cb1[t]; ob2f[t] = ob2[t]; ow3f[t] = ow3[t]; }
    else if (t < 192) { ob1f[t - 64] = ob1[t - 64]; }
    else if (t < 208) { int i = t - 192; cb2f[i] = (i < 10) ? cb2[i] : 0.f; }
    // ---- zero-init padded tiles ----
    for (int i = t; i < 16 * 72;  i += 256) (&cw2B[0][0])[i] = 0;
    for (int i = t; i < 128 * 40; i += 256) (&ow1cB[0][0])[i] = 0;
    for (int i = t; i < 16 * 136; i += 256) (&ow1cTB[0][0])[i] = 0;
    for (int i = t; i < 64 * 40;  i += 256) (&cw2TB[0][0])[i] = 0;
    for (int i = t; i < 16 * 40;  i += 256) { (&cvA[0][0])[i] = 0; (&dz2A[0][0])[i] = 0; }
    __syncthreads();
    // ---- weight tiles (block-wide strided, coalesced reads) ----
    for (int i = t; i < 640; i += 256)  { int k = i / 10, n = i - k * 10;       // cw2 flat
        cw2B[n][k] = f2bf(cw2[i]); }
    for (int i = t; i < 640; i += 256)  { int n = i / 10, k = i - n * 10;
        cw2TB[n][k] = f2bf(cw2[i]); }
    for (int i = t; i < 1280; i += 256) { int k = i >> 7, n = i & 127;          // ow1c flat
        ow1cB[n][k] = f2bf(ow1[(size_t)(4096 + k) * 128 + n]); }
    for (int i = t; i < 8192; i += 256) { int k = i >> 6, n = i & 63;           // ow2 flat
        ow2B[n][k] = f2bf(ow2[i]); }
    for (int i = t; i < 2048; i += 256) { int n = i >> 4, c4 = (i & 15) * 4;    // ow2 rows
        float4 v = *reinterpret_cast<const float4*>(ow2 + n * 64 + c4);
        unsigned int p0 = (unsigned int)f2bf(v.x) | ((unsigned int)f2bf(v.y) << 16);
        unsigned int p1 = (unsigned int)f2bf(v.z) | ((unsigned int)f2bf(v.w) << 16);
        *reinterpret_cast<uint2*>(&ow2TB[n][c4]) = make_uint2(p0, p1); }
    for (int i = t; i < 320; i += 256)  { int n = i >> 5, c4 = (i & 31) * 4;    // ow1c rows
        float4 v = *reinterpret_cast<const float4*>(ow1 + (size_t)(4096 + n) * 128 + c4);
        unsigned int p0 = (unsigned int)f2bf(v.x) | ((unsigned int)f2bf(v.y) << 16);
        unsigned int p1 = (unsigned int)f2bf(v.z) | ((unsigned int)f2bf(v.w) << 16);
        *reinterpret_cast<uint2*>(&ow1cTB[n][c4]) = make_uint2(p0, p1); }
    // ---- Ts = sum_z Tparts[z][rows][:] ----
    for (int i = t; i < 768; i += 256) {
        int row = i / 48, c4 = (i - row * 48) * 4;
        const float* src = Tparts + (size_t)(b16 + row) * NW + c4;
        float4 s = make_float4(0.f, 0.f, 0.f, 0.f);
        #pragma unroll
        for (int z = 0; z < 8; ++z) {
            float4 v = *reinterpret_cast<const float4*>(src + (size_t)z * BATCH * NW);
            s.x += v.x; s.y += v.y; s.z += v.z; s.w += v.w;
        }
        *reinterpret_cast<float4*>(&Ts[row][c4]) = s;
    }
    __syncthreads();

    f32x4 ds1[2], ds2;                    // per-wave dsum slices
    ds1[0] = (f32x4){0.f, 0.f, 0.f, 0.f};
    ds1[1] = (f32x4){0.f, 0.f, 0.f, 0.f};
    ds2    = (f32x4){0.f, 0.f, 0.f, 0.f};
    float sv[4];                          // sigmoid' — wave 0 registers only

    for (int step = 0; step < 3; ++step) {
        // (1) hc = relu(T[:, :64] + cb1)
        for (int i = t; i < 1024; i += 256) { int row = i >> 6, k = i & 63;
            hcB[row][k] = f2bf(fmaxf(Ts[row][k] + cb1f[k], 0.f)); }
        __syncthreads();
        // (2) cv = sigmoid(hc @ cw2)       [wave 0]
        if (w == 0) {
            f32x4 accv = (f32x4){0.f, 0.f, 0.f, 0.f};
            #pragma unroll
            for (int h = 0; h < 2; ++h) {
                bf16x8 a = *reinterpret_cast<const bf16x8*>(&hcB[lr][h * 32 + lk]);
                bf16x8 bb = *reinterpret_cast<const bf16x8*>(&cw2B[lr][h * 32 + lk]);
                accv = __builtin_amdgcn_mfma_f32_16x16x32_bf16(a, bb, accv, 0, 0, 0);
            }
            #pragma unroll
            for (int r = 0; r < 4; ++r) {
                float c = 1.f / (1.f + __expf(-(accv[r] + cb2f[lr])));
                sv[r] = c * (1.f - c);
                cvA[lq * 4 + r][lr] = f2bf(c);
            }
        }
        __syncthreads();
        // (3) h1 = relu(T[:,64:] + ob1 + cv @ ow1c)   [2 nf per wave]
        {
            bf16x8 a = *reinterpret_cast<const bf16x8*>(&cvA[lr][lk]);
            #pragma unroll
            for (int j = 0; j < 2; ++j) {
                int nf = w * 2 + j;
                bf16x8 bb = *reinterpret_cast<const bf16x8*>(&ow1cB[nf * 16 + lr][lk]);
                f32x4 acch = __builtin_amdgcn_mfma_f32_16x16x32_bf16(a, bb,
                            (f32x4){0.f, 0.f, 0.f, 0.f}, 0, 0, 0);
                #pragma unroll
                for (int r = 0; r < 4; ++r) {
                    int row = lq * 4 + r, col = nf * 16 + lr;
                    float v = acch[r] + Ts[row][64 + col] + ob1f[col];
                    h1B[row][col] = f2bf(fmaxf(v, 0.f));
                }
            }
        }
        __syncthreads();
        // (4) dh2 = (h1@ow2+ob2 > 0) ? ow3 : 0   [1 nf per wave]
        {
            f32x4 accz = (f32x4){0.f, 0.f, 0.f, 0.f};
            #pragma unroll
            for (int kc = 0; kc < 4; ++kc) {
                bf16x8 a = *reinterpret_cast<const bf16x8*>(&h1B[lr][kc * 32 + lk]);
                bf16x8 bb = *reinterpret_cast<const bf16x8*>(&ow2B[w * 16 + lr][kc * 32 + lk]);
                accz = __builtin_amdgcn_mfma_f32_16x16x32_bf16(a, bb, accz, 0, 0, 0);
            }
            #pragma unroll
            for (int r = 0; r < 4; ++r) {
                int col = w * 16 + lr;
                float z = accz[r] + ob2f[col];
                dh2B[lq * 4 + r][col] = f2bf((z > 0.f) ? ow3f[col] : 0.f);
            }
        }
        __syncthreads();
        // (5) dh1 = (h1>0) * (dh2 @ ow2^T)   [2 nf per wave]
        #pragma unroll
        for (int j = 0; j < 2; ++j) {
            int nf = w * 2 + j;
            f32x4 accd = (f32x4){0.f, 0.f, 0.f, 0.f};
            #pragma unroll
            for (int kc = 0; kc < 2; ++kc) {
                bf16x8 a = *reinterpret_cast<const bf16x8*>(&dh2B[lr][kc * 32 + lk]);
                bf16x8 bb = *reinterpret_cast<const bf16x8*>(&ow2TB[nf * 16 + lr][kc * 32 + lk]);
                accd = __builtin_amdgcn_mfma_f32_16x16x32_bf16(a, bb, accd, 0, 0, 0);
            }
            #pragma unroll
            for (int r = 0; r < 4; ++r) {
                int row = lq * 4 + r, col = nf * 16 + lr;
                float v = (bf2f(h1B[row][col]) > 0.f) ? accd[r] : 0.f;
                ds1[j][r] += v;
                dh1B[row][col] = f2bf(v);
            }
        }
        __syncthreads();
        // (6) dz2 = (dh1 @ ow1c^T) * cv*(1-cv)   [wave 0]
        if (w == 0) {
            f32x4 accq = (f32x4){0.f, 0.f, 0.f, 0.f};
            #pragma unroll
            for (int kc = 0; kc < 4; ++kc) {
                bf16x8 a = *reinterpret_cast<const bf16x8*>(&dh1B[lr][kc * 32 + lk]);
                bf16x8 bb = *reinterpret_cast<const bf16x8*>(&ow1cTB[lr][kc * 32 + lk]);
                accq = __builtin_amdgcn_mfma_f32_16x16x32_bf16(a, bb, accq, 0, 0, 0);
            }
            #pragma unroll
            for (int r = 0; r < 4; ++r)
                dz2A[lq * 4 + r][lr] = f2bf(accq[r] * sv[r]);
        }
        __syncthreads();
        // (7) dhc = (hc>0) * (dz2 @ cw2^T)   [1 nf per wave]
        {
            bf16x8 a = *reinterpret_cast<const bf16x8*>(&dz2A[lr][lk]);
            bf16x8 bb = *reinterpret_cast<const bf16x8*>(&cw2TB[w * 16 + lr][lk]);
            f32x4 accc = __builtin_amdgcn_mfma_f32_16x16x32_bf16(a, bb,
                        (f32x4){0.f, 0.f, 0.f, 0.f}, 0, 0, 0);
            #pragma unroll
            for (int r = 0; r < 4; ++r) {
                int row = lq * 4 + r, col = w * 16 + lr;
                float v = (bf2f(hcB[row][col]) > 0.f) ? accc[r] : 0.f;
                ds2[r] += v;
                dhcB[row][col] = f2bf(v);
            }
        }
        __syncthreads();
        // (8) T -= 0.01 * [dhc | dh1] @ Gram   [3 nf per wave]
        if (step < 2) {
            f32x4 accT[3];
            #pragma unroll
            for (int j = 0; j < 3; ++j) accT[j] = (f32x4){0.f, 0.f, 0.f, 0.f};
            #pragma unroll
            for (int kf = 0; kf < 6; ++kf) {
                bf16x8 a = (kf < 2)
                    ? *reinterpret_cast<const bf16x8*>(&dhcB[lr][kf * 32 + lk])
                    : *reinterpret_cast<const bf16x8*>(&dh1B[lr][(kf - 2) * 32 + lk]);
                #pragma unroll
                for (int j = 0; j < 3; ++j) {
                    int nf = w * 3 + j;
                    bf16x8 bg = *reinterpret_cast<const bf16x8*>(
                        Gram + (size_t)(nf * 16 + lr) * NW + kf * 32 + lk);
                    accT[j] = __builtin_amdgcn_mfma_f32_16x16x32_bf16(a, bg, accT[j], 0, 0, 0);
                }
            }
            #pragma unroll
            for (int j = 0; j < 3; ++j)
                #pragma unroll
                for (int r = 0; r < 4; ++r)
                    Ts[lq * 4 + r][(w * 3 + j) * 16 + lr] -= 0.01f * accT[j][r];
            __syncthreads();
        }
    }
    // Dsbf = [sum dh1 | sum dhc] bf16 — each wave writes its N-slices
    #pragma unroll
    for (int j = 0; j < 2; ++j)
        #pragma unroll
        for (int r = 0; r < 4; ++r)
            Dsbf[(size_t)(b16 + lq * 4 + r) * NW + (w * 2 + j) * 16 + lr] = f2bf(ds1[j][r]);
    #pragma unroll
    for (int r = 0; r < 4; ++r)
        Dsbf[(size_t)(b16 + lq * 4 + r) * NW + 128 + w * 16 + lr] = f2bf(ds2[r]);
}

// ============ L5: pm = tanh(0.7e+0.3enc) - 0.01 * Dsum @ Wcat^T ============
// v2: corrections bounced through LDS (bf16, overlaid on dead Bs tile);
//     epilogue is a fully-coalesced float2 stream (fixed cols per thread).
__global__ __launch_bounds__(256) void final_k(const unsigned short* __restrict__ Dsbf,
        const unsigned short* __restrict__ Wcat, const float* __restrict__ tp,
        const float* __restrict__ cons, const float* __restrict__ e,
        float* __restrict__ pm) {
    __shared__ __align__(16) unsigned short As[64][72];
    __shared__ __align__(16) unsigned short Bs[256][72];           // 36864 B
    unsigned short (*corr)[264] = reinterpret_cast<unsigned short(*)[264]>(&Bs[0][0]); // 33792 B overlay
    const int bid = blockIdx.x, t = threadIdx.x;
    const int m0 = (bid >> 4) * 64;
    const int n0 = (bid & 15) * 256;
    const int w = t >> 6, l = t & 63;
    const int lr = l & 15, lq = l >> 4, lk = lq * 8;

    f32x4 acc[16];
    #pragma unroll
    for (int nf = 0; nf < 16; ++nf) acc[nf] = (f32x4){0.f, 0.f, 0.f, 0.f};

    for (int kt = 0; kt < NW; kt += 64) {
        #pragma unroll
        for (int c = 0; c < 2; ++c) {      // A: Dsbf 64x64
            int ch = t + c * 256;
            int row = ch >> 3, col8 = (ch & 7) * 8;
            *reinterpret_cast<float4*>(&As[row][col8]) =
                *reinterpret_cast<const float4*>(Dsbf + (size_t)(m0 + row) * NW + kt + col8);
        }
        #pragma unroll
        for (int c = 0; c < 8; ++c) {      // B: Wcat 256x64
            int ch = t + c * 256;
            int row = ch >> 3, col8 = (ch & 7) * 8;
            *reinterpret_cast<float4*>(&Bs[row][col8]) =
                *reinterpret_cast<const float4*>(Wcat + (size_t)(n0 + row) * NW + kt + col8);
        }
        __syncthreads();
        #pragma unroll
        for (int h = 0; h < 2; ++h) {
            bf16x8 a = *reinterpret_cast<const bf16x8*>(&As[w * 16 + lr][h * 32 + lk]);
            #pragma unroll
            for (int nf = 0; nf < 16; ++nf) {
                bf16x8 b = *reinterpret_cast<const bf16x8*>(&Bs[nf * 16 + lr][h * 32 + lk]);
                acc[nf] = __builtin_amdgcn_mfma_f32_16x16x32_bf16(a, b, acc[nf], 0, 0, 0);
            }
        }
        __syncthreads();                   // last one also guards the Bs->corr overlay
    }
    // ---- stage corrections 0.01*acc into LDS (bf16) in fragment order ----
    const int lrow = w * 16 + lq * 4;
    #pragma unroll
    for (int nf = 0; nf < 16; ++nf)
        #pragma unroll
        for (int r = 0; r < 4; ++r)
            corr[lrow + r][nf * 16 + lr] = f2bf(0.01f * acc[nf][r]);
    __syncthreads();
    // ---- coalesced stream: thread owns 2 fixed cols, marches 64 rows ----
    const int c2 = (t & 127) * 2;          // local col pair 0..254
    const int rbase = t >> 7;              // 0 or 1
    const int n = n0 + c2;
    if (n + 1 < PAR) {                     // fast path (all tiles except n0==3840)
        const float2 ev = *reinterpret_cast<const float2*>(e + n);
        const float a0 = 0.7f * ev.x, a1 = 0.7f * ev.y;
        #pragma unroll 8
        for (int it = 0; it < 32; ++it) {
            int row = it * 2 + rbase;
            int m = m0 + row;
            float2 tv = *reinterpret_cast<const float2*>(tp + (size_t)m * PAR + n);
            unsigned int cw = *reinterpret_cast<const unsigned int*>(&corr[row][c2]);
            float2 o;
            o.x = fast_tanh(a0 + 0.3f * tv.x) - bf2f((unsigned short)(cw & 0xFFFF));
            o.y = fast_tanh(a1 + 0.3f * tv.y) - bf2f((unsigned short)(cw >> 16));
            *reinterpret_cast<float2*>(pm + (size_t)m * PDIM + n) = o;
        }
    } else {                               // boundary tile: per-element
        const float e0 = e[n], e1 = e[n + 1];
        for (int it = 0; it < 32; ++it) {
            int row = it * 2 + rbase;
            int m = m0 + row;
            unsigned int cw = *reinterpret_cast<const unsigned int*>(&corr[row][c2]);
            float v0 = (n < PAR) ? tp[(size_t)m * PAR + n] : cons[m * CONS + (n - PAR)];
            float v1 = (n + 1 < PAR) ? tp[(size_t)m * PAR + n + 1] : cons[m * CONS + (n + 1 - PAR)];
            pm[(size_t)m * PDIM + n]     = fast_tanh(0.7f * e0 + 0.3f * v0) - bf2f((unsigned short)(cw & 0xFFFF));
            pm[(size_t)m * PDIM + n + 1] = fast_tanh(0.7f * e1 + 0.3f * v1) - bf2f((unsigned short)(cw >> 16));
        }
    }
}

extern "C" void kernel_launch(void* const* d_in, const int* in_sizes, int n_in,
                              void* d_out, int out_size, void* d_ws, size_t ws_size,
                              hipStream_t stream) {
    const float* tp   = (const float*)d_in[0];
    const float* cons = (const float*)d_in[1];
    // d_in[2] transverse_field, d_in[3] coupling: DEAD CODE (annealing is identity)
    const float* mp   = (const float*)d_in[4];
    const float* cw1  = (const float*)d_in[5];
    const float* cb1  = (const float*)d_in[6];
    const float* cw2  = (const float*)d_in[7];
    const float* cb2  = (const float*)d_in[8];
    const float* ow1  = (const float*)d_in[9];
    const float* ob1  = (const float*)d_in[10];
    const float* ow2  = (const float*)d_in[11];
    const float* ob2  = (const float*)d_in[12];
    const float* ow3  = (const float*)d_in[13];
    float* pm = (float*)d_out;

    float* f = (float*)d_ws;
    float* e      = f;  f += 4096;
    float* epart  = f;  f += 32 * 4096;
    float* Gpart  = f;  f += 8 * NW * NW;
    float* Tparts = f;  f += 8 * BATCH * NW;
    unsigned short* u = (unsigned short*)f;
    unsigned short* WT   = u;  u += NW * PDIM;
    unsigned short* Wcat = u;  u += PDIM * NW;
    unsigned short* Gram = u;  u += NW * NW;
    unsigned short* Dsbf = u;

    prep_all_k<<<3968, 256, 0, stream>>>(mp, cw1, ow1, epart, WT, Wcat);
    fin_gram_k<<<88, 256, 0, stream>>>(epart, WT, e, Gpart);
    gemmT_k<<<400, 256, 0, stream>>>(tp, cons, e, WT, Tparts, Gpart, Gram);
    refine_k<<<128, 256, 0, stream>>>(Tparts, cb1, cw2, cb2, ow1, ob1, ow2, ob2, ow3,
                                      Gram, Dsbf);
    final_k<<<512, 256, 0, stream>>>(Dsbf, Wcat, tp, cons, e, pm);
}